// Round 3
// baseline (621.264 us; speedup 1.0000x reference)
//
#include <hip/hip_runtime.h>
#include <hip/hip_cooperative_groups.h>
#include <cstddef>

namespace cg = cooperative_groups;

#define B 8

constexpr float DM = 0.95122942450071400910f; // exp(-1/20) in f32
constexpr float DS = 0.81873075307798185867f; // exp(-1/5) in f32

constexpr int N_IN = B * 3 * 32 * 32;     // 24576
constexpr int N_L1 = B * 64 * 32 * 32;    // 524288
constexpr int N_L2 = B * 128 * 32 * 32;   // 1048576
constexpr int N_P1 = B * 128 * 16 * 16;   // 262144
constexpr int N_L3 = B * 256 * 16 * 16;   // 524288
constexpr int N_P2 = B * 256 * 8 * 8;     // 131072
constexpr int N_L4 = B * 512 * 8 * 8;     // 262144
constexpr int N_L5 = B * 256 * 8 * 8;     // 131072
constexpr int N_F1 = B * 1024;            // 8192
constexpr int N_F2 = B * 512;             // 4096
constexpr int N_F3 = B * 10;              // 80

// ---- workspace float layout ----
constexpr size_t O_IN_U = 0;  // unused (encode is in-register) but kept in layout
constexpr size_t O_UM1 = O_IN_U + N_IN;
constexpr size_t O_US1 = O_UM1 + N_L1;
constexpr size_t O_UM2 = O_US1 + N_L1;
constexpr size_t O_US2 = O_UM2 + N_L2;
constexpr size_t O_P1E = O_US2 + N_L2;
constexpr size_t O_UM3 = O_P1E + N_L2;
constexpr size_t O_US3 = O_UM3 + N_L3;
constexpr size_t O_P2E = O_US3 + N_L3;
constexpr size_t O_UM4 = O_P2E + N_L3;
constexpr size_t O_US4 = O_UM4 + N_L4;
constexpr size_t O_UM5 = O_US4 + N_L4;
constexpr size_t O_US5 = O_UM5 + N_L5;
constexpr size_t O_UMF1 = O_US5 + N_L5;
constexpr size_t O_USF1 = O_UMF1 + N_F1;
constexpr size_t O_UMF2 = O_USF1 + N_F1;
constexpr size_t O_USF2 = O_UMF2 + N_F2;
constexpr size_t O_UMF3 = O_USF2 + N_F2;
constexpr size_t O_USF3 = O_UMF3 + N_F3;
constexpr size_t O_TE = O_USF3 + N_F3;
constexpr size_t ZEND = O_TE + N_F3;
// ones-initialized region (sav)
constexpr size_t O_SAV1 = ZEND;
constexpr size_t O_SAV2 = O_SAV1 + N_L1;
constexpr size_t O_SAV3 = O_SAV2 + N_L2;
constexpr size_t O_SAV4 = O_SAV3 + N_L3;
constexpr size_t O_SAV5 = O_SAV4 + N_L4;
constexpr size_t O_SAVF1 = O_SAV5 + N_L5;
constexpr size_t O_SAVF2 = O_SAVF1 + N_F1;
constexpr size_t O_SAVF3 = O_SAVF2 + N_F2;
constexpr size_t OEND = O_SAVF3 + N_F3;
// eight-initialized region (latency maps)
constexpr size_t O_P1L = OEND;
constexpr size_t O_P2L = O_P1L + N_L2;
constexpr size_t EEND = O_P2L + N_L3;
constexpr size_t FLOAT_TOTAL = EEND;
// ---- workspace int layout (after floats) ----
constexpr size_t I_L0 = 0;                      // 8 per-step input spike lists
constexpr size_t I_L1 = I_L0 + 8 * (size_t)N_IN;
constexpr size_t I_L2P = I_L1 + N_L1;
constexpr size_t I_L3P = I_L2P + N_P1;
constexpr size_t I_L4 = I_L3P + N_P2;
constexpr size_t I_L5 = I_L4 + N_L4;
constexpr size_t I_LF1 = I_L5 + N_L5;
constexpr size_t I_LF2 = I_LF1 + N_F1;
constexpr size_t I_CNT = I_LF2 + N_F2;          // 64 counters (8 steps x 8 layers)
constexpr size_t INT_TOTAL = I_CNT + 64;
constexpr size_t WS_NEED = FLOAT_TOTAL * sizeof(float) + INT_TOTAL * sizeof(int);

__device__ __forceinline__ int ldcnt(const int* p) {
  return __hip_atomic_load(p, __ATOMIC_RELAXED, __HIP_MEMORY_SCOPE_AGENT);
}

// wave-aggregated compaction: 1 atomic per wave; also bumps the sum_sp slot if given
__device__ __forceinline__ void wave_append(bool sp, int idx, int* cnt, int* list,
                                            float* sum_slot) {
  unsigned long long bal = __ballot(sp);
  if (bal == 0ull) return;
  int lane = threadIdx.x & 63;
  int leader = (int)__ffsll((unsigned long long)bal) - 1;
  int base = 0;
  if (lane == leader) {
    int n = __popcll(bal);
    base = atomicAdd(cnt, n);
    if (sum_slot) atomicAdd(sum_slot, (float)n);
  }
  base = __shfl(base, leader);
  if (sp) {
    int rank = __popcll(bal & ((1ull << lane) - 1ull));
    list[base + rank] = idx;
  }
}

// fused conv layer phase: LDS spike-scatter + NOSO update (+ pe/pl + latency min-pool) + compact
template <int CIN, int COUT, int H, int W, bool POOL>
__device__ void conv_phase(int wgid, int nwg, int tid, const int* __restrict__ list, int S,
                           const float* __restrict__ w, float* __restrict__ um,
                           float* __restrict__ us, float* __restrict__ sav,
                           float* __restrict__ pe, float* __restrict__ pl,
                           int* __restrict__ out_list, int* __restrict__ out_cnt,
                           float* __restrict__ sum_slot, float* s_acc, float* s_plb,
                           float* s_spb) {
  constexpr int HW = H * W;
  for (int plane = wgid; plane < B * COUT; plane += nwg) {
    const int b = plane / COUT, oc = plane % COUT;
    for (int p = tid; p < HW; p += 256) s_acc[p] = 0.0f;
    __syncthreads();
    for (int s = tid; s < S; s += 256) {
      int idx = list[s];
      int bs = idx / (CIN * HW);
      if (bs != b) continue;
      int r = idx - bs * (CIN * HW);
      int c = r / HW;
      int p = r - c * HW;
      int y = p / W, x = p - y * W;
      const float* wp = w + ((size_t)oc * CIN + c) * 25;
#pragma unroll
      for (int ki = 0; ki < 5; ++ki) {
        int oy = y + 2 - ki;
        if ((unsigned)oy < (unsigned)H) {
#pragma unroll
          for (int kj = 0; kj < 5; ++kj) {
            int ox = x + 2 - kj;
            if ((unsigned)ox < (unsigned)W) atomicAdd(&s_acc[oy * W + ox], wp[ki * 5 + kj]);
          }
        }
      }
    }
    __syncthreads();
    const size_t pb = (size_t)plane * HW;
    for (int p = tid; p < HW; p += 256) {
      size_t g = pb + p;
      float cv = s_acc[p];
      float m = DM * um[g] + cv;
      float s2 = DS * us[g] + cv;
      um[g] = m;
      us[g] = s2;
      float u = sav[g] * (m - s2);
      bool sp = (u - 1.0f > 0.0f);
      if (sp) sav[g] = 0.0f;
      if constexpr (POOL) {
        unsigned long long bal = __ballot(sp);
        if ((tid & 63) == 0 && bal) atomicAdd(sum_slot, (float)__popcll(bal));
        float pe_old = pe[g];
        float act = (m != 0.0f) ? 1.0f : 0.0f;
        float pe_new = pe_old + (((pe_old + act) != 0.0f) ? 1.0f : 0.0f);
        pe[g] = pe_new;
        float plv = pl[g];
        if (sp) {
          plv += pe_new - 7.0f;  // pl += sp * (pe - NUM_STEPS + 1)
          pl[g] = plv;
        }
        s_plb[p] = plv;
        s_spb[p] = sp ? 1.0f : 0.0f;
      } else {
        wave_append(sp, (int)g, out_cnt, out_list, sum_slot);
      }
    }
    if constexpr (POOL) {
      __syncthreads();
      constexpr int HP = H / 2, WP = W / 2;
      for (int q = tid; q < HP * WP; q += 256) {
        int py = q / WP, px = q - py * WP;
        int b2 = (2 * py) * W + 2 * px;
        float l0 = s_plb[b2], l1 = s_plb[b2 + 1], l2 = s_plb[b2 + W], l3 = s_plb[b2 + W + 1];
        int off = 0;
        float lm = l0;
        if (l1 < lm) { lm = l1; off = 1; }
        if (l2 < lm) { lm = l2; off = W; }
        if (l3 < lm) { lm = l3; off = W + 1; }
        bool psp = (s_spb[b2 + off] != 0.0f);
        wave_append(psp, plane * (HP * WP) + q, out_cnt, out_list, nullptr);
      }
    }
    __syncthreads();
  }
}

// fused FC layer phase: quad-split gather + NOSO update + compact
template <int IN, int OUT>
__device__ void fc_phase(int gt, int gsz, const int* __restrict__ list, int S,
                         const float* __restrict__ w, float* __restrict__ um,
                         float* __restrict__ us, float* __restrict__ sav,
                         int* __restrict__ out_list, int* __restrict__ out_cnt,
                         float* __restrict__ sum_slot) {
  for (int q = gt; q < B * OUT * 4; q += gsz) {
    int oi = q >> 2, sub = q & 3;
    int b = oi / OUT, o = oi - b * OUT;
    float acc = 0.0f;
    for (int s = sub; s < S; s += 4) {
      int idx = list[s];
      int bs = idx / IN;
      if (bs == b) acc += w[(size_t)o * IN + (idx - bs * IN)];
    }
    acc += __shfl_xor(acc, 1);
    acc += __shfl_xor(acc, 2);
    bool sp = false;
    int gidx = b * OUT + o;
    if (sub == 0) {
      float m = DM * um[gidx] + acc;
      float s2 = DS * us[gidx] + acc;
      um[gidx] = m;
      us[gidx] = s2;
      float u = sav[gidx] * (m - s2);
      sp = (u - 1.0f > 0.0f);
      if (sp) sav[gidx] = 0.0f;
    }
    wave_append(sp, gidx, out_cnt, out_list, sum_slot);
  }
}

// final FC (512->10) + te/out_t/out_u epilogue, single WG
__device__ void fc3_phase(int wgid, int tid, const int* __restrict__ list, int S,
                          const float* __restrict__ w, float* __restrict__ um,
                          float* __restrict__ us, float* __restrict__ sav,
                          float* __restrict__ te, float* __restrict__ out) {
  if (wgid != 0 || tid >= N_F3) return;
  int b = tid / 10, o = tid - b * 10;
  float cv = 0.0f;
  for (int s = 0; s < S; ++s) {
    int idx = list[s];
    int bs = idx >> 9;
    if (bs == b) cv += w[o * 512 + (idx & 511)];
  }
  float m = DM * um[tid] + cv;
  float s2 = DS * us[tid] + cv;
  um[tid] = m;
  us[tid] = s2;
  float u = sav[tid] * (m - s2);
  float sp = (u - 1.0f > 0.0f) ? 1.0f : 0.0f;
  if (sp != 0.0f) sav[tid] = 0.0f;
  float t_old = te[tid];
  float act = (u != 0.0f) ? 1.0f : 0.0f;
  float t_new = t_old + (((t_old + act) != 0.0f) ? 1.0f : 0.0f);
  te[tid] = t_new;
  out[tid] += sp * (t_new - 8.0f);  // out_t (dodt forward)
  out[80 + tid] += sp * u;          // out_u
  if (sp != 0.0f) atomicAdd(&out[168], 1.0f);
}

__global__ __launch_bounds__(256, 2) void k_noso(const float* __restrict__ input,
                                                 const float* wc1, const float* wc2,
                                                 const float* wc3, const float* wc4,
                                                 const float* wc5, const float* wf1,
                                                 const float* wf2, const float* wf3,
                                                 float* __restrict__ out, float* __restrict__ ws,
                                                 int* __restrict__ iws) {
  cg::grid_group grid = cg::this_grid();
  const int tid = threadIdx.x;
  const int wgid = blockIdx.x;
  const int nwg = gridDim.x;
  const int gt = wgid * 256 + tid;
  const int gsz = nwg * 256;
  __shared__ float s_acc[1024];
  __shared__ float s_plb[1024];
  __shared__ float s_spb[1024];
  int* cnt = iws + I_CNT;

  // P0: init all state (zeros / sav=1 / latency=8), counters, out (out_t=8, rest 0)
  for (size_t i = (size_t)gt; i < FLOAT_TOTAL; i += gsz)
    ws[i] = (i < ZEND) ? 0.0f : (i < OEND ? 1.0f : 8.0f);
  if (gt < 64) cnt[gt] = 0;
  if (gt < 169) out[gt] = (gt < 80) ? 8.0f : 0.0f;
  __threadfence();
  grid.sync();

  // P1: encode all 8 steps (in-register recurrence), build per-step input spike lists
  for (int i = gt; i < N_IN; i += gsz) {
    float x = input[i] * 0.2f;
    float u = 0.0f;
#pragma unroll
    for (int t = 0; t < 8; ++t) {
      u = DM * u + x;
      bool sp = (u - 1.0f > 0.0f);
      if (sp) u = 0.0f;
      wave_append(sp, i, cnt + t * 8 + 0, iws + I_L0 + (size_t)t * N_IN, out + 160);
    }
  }
  __threadfence();
  grid.sync();

  // main loop with sticky activity gating; every barrier is taken uniformly by all WGs
  bool act1 = false, act2 = false, act3 = false, act4 = false;
  bool act5 = false, act6 = false, act7 = false, act8 = false;
  for (int t = 0; t < 8; ++t) {
    int* c = cnt + t * 8;
    act1 = act1 || (ldcnt(c + 0) > 0);
    if (act1) {
      conv_phase<3, 64, 32, 32, false>(wgid, nwg, tid, iws + I_L0 + (size_t)t * N_IN,
                                       ldcnt(c + 0), wc1, ws + O_UM1, ws + O_US1, ws + O_SAV1,
                                       nullptr, nullptr, iws + I_L1, c + 1, out + 161, s_acc,
                                       s_plb, s_spb);
      __threadfence();
      grid.sync();
      act2 = act2 || (ldcnt(c + 1) > 0);
    }
    if (act2) {
      conv_phase<64, 128, 32, 32, true>(wgid, nwg, tid, iws + I_L1, ldcnt(c + 1), wc2,
                                        ws + O_UM2, ws + O_US2, ws + O_SAV2, ws + O_P1E,
                                        ws + O_P1L, iws + I_L2P, c + 2, out + 162, s_acc, s_plb,
                                        s_spb);
      __threadfence();
      grid.sync();
      act3 = act3 || (ldcnt(c + 2) > 0);
    }
    if (act3) {
      conv_phase<128, 256, 16, 16, true>(wgid, nwg, tid, iws + I_L2P, ldcnt(c + 2), wc3,
                                         ws + O_UM3, ws + O_US3, ws + O_SAV3, ws + O_P2E,
                                         ws + O_P2L, iws + I_L3P, c + 3, out + 163, s_acc, s_plb,
                                         s_spb);
      __threadfence();
      grid.sync();
      act4 = act4 || (ldcnt(c + 3) > 0);
    }
    if (act4) {
      conv_phase<256, 512, 8, 8, false>(wgid, nwg, tid, iws + I_L3P, ldcnt(c + 3), wc4,
                                        ws + O_UM4, ws + O_US4, ws + O_SAV4, nullptr, nullptr,
                                        iws + I_L4, c + 4, out + 164, s_acc, s_plb, s_spb);
      __threadfence();
      grid.sync();
      act5 = act5 || (ldcnt(c + 4) > 0);
    }
    if (act5) {
      conv_phase<512, 256, 8, 8, false>(wgid, nwg, tid, iws + I_L4, ldcnt(c + 4), wc5,
                                        ws + O_UM5, ws + O_US5, ws + O_SAV5, nullptr, nullptr,
                                        iws + I_L5, c + 5, out + 165, s_acc, s_plb, s_spb);
      __threadfence();
      grid.sync();
      act6 = act6 || (ldcnt(c + 5) > 0);
    }
    if (act6) {
      fc_phase<16384, 1024>(gt, gsz, iws + I_L5, ldcnt(c + 5), wf1, ws + O_UMF1, ws + O_USF1,
                            ws + O_SAVF1, iws + I_LF1, c + 6, out + 166);
      __threadfence();
      grid.sync();
      act7 = act7 || (ldcnt(c + 6) > 0);
    }
    if (act7) {
      fc_phase<1024, 512>(gt, gsz, iws + I_LF1, ldcnt(c + 6), wf2, ws + O_UMF2, ws + O_USF2,
                          ws + O_SAVF2, iws + I_LF2, c + 7, out + 167);
      __threadfence();
      grid.sync();
      act8 = act8 || (ldcnt(c + 7) > 0);
    }
    if (act8) {
      fc3_phase(wgid, tid, iws + I_LF2, ldcnt(c + 7), wf3, ws + O_UMF3, ws + O_USF3,
                ws + O_SAVF3, ws + O_TE, out);
      // no barrier needed: fc3 state/out are private to WG0 and re-read only by fc3 next step
    }
  }
}

extern "C" void kernel_launch(void* const* d_in, const int* in_sizes, int n_in, void* d_out,
                              int out_size, void* d_ws, size_t ws_size, hipStream_t stream) {
  const float* input = (const float*)d_in[0];
  const float* wc1 = (const float*)d_in[1];
  const float* wc2 = (const float*)d_in[2];
  const float* wc3 = (const float*)d_in[3];
  const float* wc4 = (const float*)d_in[4];
  const float* wc5 = (const float*)d_in[5];
  const float* wf1 = (const float*)d_in[6];
  const float* wf2 = (const float*)d_in[7];
  const float* wf3 = (const float*)d_in[8];
  float* out = (float*)d_out;
  float* ws = (float*)d_ws;
  int* iws = (int*)((char*)d_ws + FLOAT_TOTAL * sizeof(float));
  if (ws_size < WS_NEED) return;  // ~47 MB needed

  void* args[] = {&input, &wc1, &wc2, &wc3, &wc4, &wc5, &wf1, &wf2, &wf3, &out, &ws, &iws};
  hipLaunchCooperativeKernel((void*)k_noso, dim3(512), dim3(256), args, 0, stream);
}

// Round 4
// 127.853 us; speedup vs baseline: 4.8592x; 4.8592x over previous
//
#include <hip/hip_runtime.h>
#include <cstddef>

#define B 8

constexpr float DM = 0.95122942450071400910f; // exp(-1/20) in f32
constexpr float DS = 0.81873075307798185867f; // exp(-1/5) in f32

constexpr int N_IN = B * 3 * 32 * 32;     // 24576
constexpr int N_L1 = B * 64 * 32 * 32;    // 524288
constexpr int N_L2 = B * 128 * 32 * 32;   // 1048576
constexpr int N_P1 = B * 128 * 16 * 16;   // 262144
constexpr int N_L3 = B * 256 * 16 * 16;   // 524288
constexpr int N_P2 = B * 256 * 8 * 8;     // 131072
constexpr int N_L4 = B * 512 * 8 * 8;     // 262144
constexpr int N_L5 = B * 256 * 8 * 8;     // 131072
constexpr int N_F1 = B * 1024;            // 8192
constexpr int N_F2 = B * 512;             // 4096
constexpr int N_F3 = B * 10;              // 80

// ---- float workspace layout ----
// zeros
constexpr size_t O_UM1 = 0;
constexpr size_t O_US1 = O_UM1 + N_L1;
constexpr size_t O_UM2 = O_US1 + N_L1;
constexpr size_t O_US2 = O_UM2 + N_L2;
constexpr size_t O_P1E = O_US2 + N_L2;
constexpr size_t O_UM3 = O_P1E + N_L2;
constexpr size_t O_US3 = O_UM3 + N_L3;
constexpr size_t O_P2E = O_US3 + N_L3;
constexpr size_t O_UM4 = O_P2E + N_L3;
constexpr size_t O_US4 = O_UM4 + N_L4;
constexpr size_t O_UM5 = O_US4 + N_L4;
constexpr size_t O_US5 = O_UM5 + N_L5;
constexpr size_t O_UMF1 = O_US5 + N_L5;
constexpr size_t O_USF1 = O_UMF1 + N_F1;
constexpr size_t O_UMF2 = O_USF1 + N_F1;
constexpr size_t O_USF2 = O_UMF2 + N_F2;
constexpr size_t O_UMF3 = O_USF2 + N_F2;
constexpr size_t O_USF3 = O_UMF3 + N_F3;
constexpr size_t O_TE = O_USF3 + N_F3;
constexpr size_t ZEND = O_TE + N_F3;
// ones (sav)
constexpr size_t O_SAV1 = ZEND;
constexpr size_t O_SAV2 = O_SAV1 + N_L1;
constexpr size_t O_SAV3 = O_SAV2 + N_L2;
constexpr size_t O_SAV4 = O_SAV3 + N_L3;
constexpr size_t O_SAV5 = O_SAV4 + N_L4;
constexpr size_t O_SAVF1 = O_SAV5 + N_L5;
constexpr size_t O_SAVF2 = O_SAVF1 + N_F1;
constexpr size_t O_SAVF3 = O_SAVF2 + N_F2;
constexpr size_t OEND = O_SAVF3 + N_F3;
// eights (latency maps)
constexpr size_t O_P1L = OEND;
constexpr size_t O_P2L = O_P1L + N_L2;
constexpr size_t EEND = O_P2L + N_L3;
constexpr size_t FLOAT_TOTAL = EEND;
// ---- int workspace layout (per-step spike lists: 8 buffers each) ----
constexpr size_t I_L0 = 0;
constexpr size_t I_L1 = I_L0 + 8 * (size_t)N_IN;
constexpr size_t I_L2P = I_L1 + 8 * (size_t)N_L1;
constexpr size_t I_L3P = I_L2P + 8 * (size_t)N_P1;
constexpr size_t I_L4 = I_L3P + 8 * (size_t)N_P2;
constexpr size_t I_L5 = I_L4 + 8 * (size_t)N_L4;
constexpr size_t I_LF1 = I_L5 + 8 * (size_t)N_L5;
constexpr size_t I_LF2 = I_LF1 + 8 * (size_t)N_F1;
constexpr size_t I_CNT = I_LF2 + 8 * (size_t)N_F2;  // 64 counters [t][layer]
constexpr size_t I_FLAG = I_CNT + 64;               // 8 sticky activity flags
constexpr size_t INT_TOTAL = I_FLAG + 8;
constexpr size_t WS_NEED = FLOAT_TOTAL * sizeof(float) + INT_TOTAL * sizeof(int);

// block budget per diagonal dispatch
constexpr int CV1_B = 512, CV2_B = 512, CV3_B = 512, CV4_B = 512, CV5_B = 256;
constexpr int FC1_B = 32, FC2_B = 16, FC3_B = 1;
constexpr int CV1_O = 0;
constexpr int CV2_O = CV1_O + CV1_B;
constexpr int CV3_O = CV2_O + CV2_B;
constexpr int CV4_O = CV3_O + CV3_B;
constexpr int CV5_O = CV4_O + CV4_B;
constexpr int FC1_O = CV5_O + CV5_B;
constexpr int FC2_O = FC1_O + FC1_B;
constexpr int FC3_O = FC2_O + FC2_B;
constexpr int DIAG_BLOCKS = FC3_O + FC3_B;  // 2353

__device__ __forceinline__ int ldcnt(const int* p) {
  return __hip_atomic_load(p, __ATOMIC_RELAXED, __HIP_MEMORY_SCOPE_AGENT);
}

// wave-aggregated compaction: 1 atomic per wave; optionally bumps sum_sp slot
__device__ __forceinline__ void wave_append(bool sp, int idx, int* cnt, int* list,
                                            float* sum_slot) {
  unsigned long long bal = __ballot(sp);
  if (bal == 0ull) return;
  int lane = threadIdx.x & 63;
  int leader = (int)__ffsll((unsigned long long)bal) - 1;
  int base = 0;
  if (lane == leader) {
    int n = __popcll(bal);
    base = atomicAdd(cnt, n);
    if (sum_slot) atomicAdd(sum_slot, (float)n);
  }
  base = __shfl(base, leader);
  if (sp) {
    int rank = __popcll(bal & ((1ull << lane) - 1ull));
    list[base + rank] = idx;
  }
}

__global__ void k_init_fill(float* __restrict__ ws, float* __restrict__ out) {
  constexpr size_t n1 = OEND - ZEND, n2 = EEND - OEND;
  size_t i = (size_t)blockIdx.x * blockDim.x + threadIdx.x;
  size_t st = (size_t)gridDim.x * blockDim.x;
  for (; i < n1 + n2 + 169; i += st) {
    if (i < n1) ws[ZEND + i] = 1.0f;
    else if (i < n1 + n2) ws[OEND + (i - n1)] = 8.0f;
    else {
      int j = (int)(i - n1 - n2);
      out[j] = (j < 80) ? 8.0f : 0.0f;  // out_t starts at NUM_STEPS
    }
  }
}

// input encoding, all 8 steps in-register; emits per-step spike lists
__global__ void k_encode(const float* __restrict__ in, int* __restrict__ iws,
                         float* __restrict__ out) {
  int i = blockIdx.x * 256 + threadIdx.x;
  if (i >= N_IN) return;  // N_IN % 256 == 0: no partial waves
  int* cnt = iws + I_CNT;
  float x = in[i] * 0.2f;
  float u = 0.0f;
#pragma unroll
  for (int t = 0; t < 8; ++t) {
    u = DM * u + x;
    bool sp = (u - 1.0f > 0.0f);
    if (sp) u = 0.0f;
    wave_append(sp, i, cnt + t * 8 + 0, iws + I_L0 + (size_t)t * N_IN, out + 160);
  }
}

// conv cell: sticky-gate + LDS spike-scatter + NOSO update (+ pe/pl + latency min-pool) + compact
template <int CIN, int COUT, int H, int W, bool POOL>
__device__ void cell_conv(int lwg, int nwg, const int* __restrict__ list,
                          const int* __restrict__ cnt_in, int* __restrict__ flag,
                          const float* __restrict__ w, float* __restrict__ um,
                          float* __restrict__ us, float* __restrict__ sav,
                          float* __restrict__ pe, float* __restrict__ pl,
                          int* __restrict__ out_list, int* __restrict__ out_cnt,
                          float* __restrict__ sum_slot, float* s_acc, float* s_plb,
                          float* s_spb) {
  const int tid = threadIdx.x;
  const int S = ldcnt(cnt_in);
  if (*flag == 0) {
    if (S == 0) return;  // layer never touched and no input: provable no-op
    if (tid == 0 && lwg == 0) *flag = 1;
  }
  constexpr int HW = H * W;
  for (int plane = lwg; plane < B * COUT; plane += nwg) {
    const int b = plane / COUT, oc = plane % COUT;
    for (int p = tid; p < HW; p += 256) s_acc[p] = 0.0f;
    __syncthreads();
    for (int s = tid; s < S; s += 256) {
      int idx = list[s];
      int bs = idx / (CIN * HW);
      if (bs != b) continue;
      int r = idx - bs * (CIN * HW);
      int c = r / HW;
      int p = r - c * HW;
      int y = p / W, x = p - y * W;
      const float* wp = w + ((size_t)oc * CIN + c) * 25;
#pragma unroll
      for (int ki = 0; ki < 5; ++ki) {
        int oy = y + 2 - ki;
        if ((unsigned)oy < (unsigned)H) {
#pragma unroll
          for (int kj = 0; kj < 5; ++kj) {
            int ox = x + 2 - kj;
            if ((unsigned)ox < (unsigned)W) atomicAdd(&s_acc[oy * W + ox], wp[ki * 5 + kj]);
          }
        }
      }
    }
    __syncthreads();
    const size_t pb = (size_t)plane * HW;
    for (int p = tid; p < HW; p += 256) {
      size_t g = pb + p;
      float cv = s_acc[p];
      float m = DM * um[g] + cv;
      float s2 = DS * us[g] + cv;
      um[g] = m;
      us[g] = s2;
      float u = sav[g] * (m - s2);
      bool sp = (u - 1.0f > 0.0f);
      if (sp) sav[g] = 0.0f;
      if constexpr (POOL) {
        unsigned long long bal = __ballot(sp);
        if ((tid & 63) == 0 && bal) atomicAdd(sum_slot, (float)__popcll(bal));
        float pe_old = pe[g];
        float act = (m != 0.0f) ? 1.0f : 0.0f;
        float pe_new = pe_old + (((pe_old + act) != 0.0f) ? 1.0f : 0.0f);
        pe[g] = pe_new;
        float plv = pl[g];
        if (sp) {
          plv += pe_new - 7.0f;  // pl += sp * (pe - NUM_STEPS + 1)
          pl[g] = plv;
        }
        s_plb[p] = plv;
        s_spb[p] = sp ? 1.0f : 0.0f;
      } else {
        wave_append(sp, (int)g, out_cnt, out_list, sum_slot);
      }
    }
    if constexpr (POOL) {
      __syncthreads();
      constexpr int HP = H / 2, WP = W / 2;
      for (int q = tid; q < HP * WP; q += 256) {
        int py = q / WP, px = q - py * WP;
        int b2 = (2 * py) * W + 2 * px;
        float l0 = s_plb[b2], l1 = s_plb[b2 + 1], l2 = s_plb[b2 + W], l3 = s_plb[b2 + W + 1];
        int off = 0;
        float lm = l0;
        if (l1 < lm) { lm = l1; off = 1; }
        if (l2 < lm) { lm = l2; off = W; }
        if (l3 < lm) { lm = l3; off = W + 1; }
        bool psp = (s_spb[b2 + off] != 0.0f);
        wave_append(psp, plane * (HP * WP) + q, out_cnt, out_list, nullptr);
      }
    }
    __syncthreads();
  }
}

// fc cell: each thread owns exactly one output neuron (block budget == B*OUT/256)
template <int IN, int OUT>
__device__ void cell_fc(int lwg, const int* __restrict__ list, const int* __restrict__ cnt_in,
                        int* __restrict__ flag, const float* __restrict__ w,
                        float* __restrict__ um, float* __restrict__ us, float* __restrict__ sav,
                        int* __restrict__ out_list, int* __restrict__ out_cnt,
                        float* __restrict__ sum_slot) {
  const int tid = threadIdx.x;
  const int S = ldcnt(cnt_in);
  if (*flag == 0) {
    if (S == 0) return;
    if (tid == 0 && lwg == 0) *flag = 1;
  }
  int q = lwg * 256 + tid;
  int b = q / OUT, o = q - b * OUT;
  float acc = 0.0f;
  for (int s = 0; s < S; ++s) {
    int idx = list[s];
    int bs = idx / IN;
    if (bs == b) acc += w[(size_t)o * IN + (idx - bs * IN)];
  }
  float m = DM * um[q] + acc;
  float s2 = DS * us[q] + acc;
  um[q] = m;
  us[q] = s2;
  float u = sav[q] * (m - s2);
  bool sp = (u - 1.0f > 0.0f);
  if (sp) sav[q] = 0.0f;
  wave_append(sp, q, out_cnt, out_list, sum_slot);
}

// final FC (512->10) + te/out_t/out_u epilogue (single block)
__device__ void cell_fc3(const int* __restrict__ list, const int* __restrict__ cnt_in,
                         int* __restrict__ flag, const float* __restrict__ w,
                         float* __restrict__ um, float* __restrict__ us,
                         float* __restrict__ sav, float* __restrict__ te,
                         float* __restrict__ out) {
  const int tid = threadIdx.x;
  const int S = ldcnt(cnt_in);
  if (*flag == 0) {
    if (S == 0) return;
    if (tid == 0) *flag = 1;
  }
  if (tid >= N_F3) return;
  int b = tid / 10, o = tid - b * 10;
  float cv = 0.0f;
  for (int s = 0; s < S; ++s) {
    int idx = list[s];
    int bs = idx >> 9;
    if (bs == b) cv += w[o * 512 + (idx & 511)];
  }
  float m = DM * um[tid] + cv;
  float s2 = DS * us[tid] + cv;
  um[tid] = m;
  us[tid] = s2;
  float u = sav[tid] * (m - s2);
  float sp = (u - 1.0f > 0.0f) ? 1.0f : 0.0f;
  if (sp != 0.0f) sav[tid] = 0.0f;
  float t_old = te[tid];
  float act = (u != 0.0f) ? 1.0f : 0.0f;
  float t_new = t_old + (((t_old + act) != 0.0f) ? 1.0f : 0.0f);
  te[tid] = t_new;
  out[tid] += sp * (t_new - 8.0f);  // out_t (dodt forward)
  out[80 + tid] += sp * u;          // out_u
  if (sp != 0.0f) atomicAdd(&out[168], 1.0f);
}

// one dispatch per anti-diagonal d = L + t: all cells independent (deps are on d-1)
__global__ __launch_bounds__(256) void k_diag(int d, const float* __restrict__ wc1,
                                              const float* __restrict__ wc2,
                                              const float* __restrict__ wc3,
                                              const float* __restrict__ wc4,
                                              const float* __restrict__ wc5,
                                              const float* __restrict__ wf1,
                                              const float* __restrict__ wf2,
                                              const float* __restrict__ wf3,
                                              float* __restrict__ out, float* __restrict__ ws,
                                              int* __restrict__ iws) {
  __shared__ float s_acc[1024];
  __shared__ float s_plb[1024];
  __shared__ float s_spb[1024];
  const int bid = blockIdx.x;
  int* cnt = iws + I_CNT;
  int* flags = iws + I_FLAG;
  if (bid < CV2_O) {
    int t = d - 1;
    if ((unsigned)t >= 8u) return;
    cell_conv<3, 64, 32, 32, false>(bid - CV1_O, CV1_B, iws + I_L0 + (size_t)t * N_IN,
                                    cnt + t * 8 + 0, flags + 0, wc1, ws + O_UM1, ws + O_US1,
                                    ws + O_SAV1, nullptr, nullptr,
                                    iws + I_L1 + (size_t)t * N_L1, cnt + t * 8 + 1, out + 161,
                                    s_acc, s_plb, s_spb);
  } else if (bid < CV3_O) {
    int t = d - 2;
    if ((unsigned)t >= 8u) return;
    cell_conv<64, 128, 32, 32, true>(bid - CV2_O, CV2_B, iws + I_L1 + (size_t)t * N_L1,
                                     cnt + t * 8 + 1, flags + 1, wc2, ws + O_UM2, ws + O_US2,
                                     ws + O_SAV2, ws + O_P1E, ws + O_P1L,
                                     iws + I_L2P + (size_t)t * N_P1, cnt + t * 8 + 2, out + 162,
                                     s_acc, s_plb, s_spb);
  } else if (bid < CV4_O) {
    int t = d - 3;
    if ((unsigned)t >= 8u) return;
    cell_conv<128, 256, 16, 16, true>(bid - CV3_O, CV3_B, iws + I_L2P + (size_t)t * N_P1,
                                      cnt + t * 8 + 2, flags + 2, wc3, ws + O_UM3, ws + O_US3,
                                      ws + O_SAV3, ws + O_P2E, ws + O_P2L,
                                      iws + I_L3P + (size_t)t * N_P2, cnt + t * 8 + 3, out + 163,
                                      s_acc, s_plb, s_spb);
  } else if (bid < CV5_O) {
    int t = d - 4;
    if ((unsigned)t >= 8u) return;
    cell_conv<256, 512, 8, 8, false>(bid - CV4_O, CV4_B, iws + I_L3P + (size_t)t * N_P2,
                                     cnt + t * 8 + 3, flags + 3, wc4, ws + O_UM4, ws + O_US4,
                                     ws + O_SAV4, nullptr, nullptr,
                                     iws + I_L4 + (size_t)t * N_L4, cnt + t * 8 + 4, out + 164,
                                     s_acc, s_plb, s_spb);
  } else if (bid < FC1_O) {
    int t = d - 5;
    if ((unsigned)t >= 8u) return;
    cell_conv<512, 256, 8, 8, false>(bid - CV5_O, CV5_B, iws + I_L4 + (size_t)t * N_L4,
                                     cnt + t * 8 + 4, flags + 4, wc5, ws + O_UM5, ws + O_US5,
                                     ws + O_SAV5, nullptr, nullptr,
                                     iws + I_L5 + (size_t)t * N_L5, cnt + t * 8 + 5, out + 165,
                                     s_acc, s_plb, s_spb);
  } else if (bid < FC2_O) {
    int t = d - 6;
    if ((unsigned)t >= 8u) return;
    cell_fc<16384, 1024>(bid - FC1_O, iws + I_L5 + (size_t)t * N_L5, cnt + t * 8 + 5, flags + 5,
                         wf1, ws + O_UMF1, ws + O_USF1, ws + O_SAVF1,
                         iws + I_LF1 + (size_t)t * N_F1, cnt + t * 8 + 6, out + 166);
  } else if (bid < FC3_O) {
    int t = d - 7;
    if ((unsigned)t >= 8u) return;
    cell_fc<1024, 512>(bid - FC2_O, iws + I_LF1 + (size_t)t * N_F1, cnt + t * 8 + 6, flags + 6,
                       wf2, ws + O_UMF2, ws + O_USF2, ws + O_SAVF2,
                       iws + I_LF2 + (size_t)t * N_F2, cnt + t * 8 + 7, out + 167);
  } else {
    int t = d - 8;
    if ((unsigned)t >= 8u) return;
    cell_fc3(iws + I_LF2 + (size_t)t * N_F2, cnt + t * 8 + 7, flags + 7, wf3, ws + O_UMF3,
             ws + O_USF3, ws + O_SAVF3, ws + O_TE, out);
  }
}

extern "C" void kernel_launch(void* const* d_in, const int* in_sizes, int n_in, void* d_out,
                              int out_size, void* d_ws, size_t ws_size, hipStream_t stream) {
  const float* input = (const float*)d_in[0];
  const float* wc1 = (const float*)d_in[1];
  const float* wc2 = (const float*)d_in[2];
  const float* wc3 = (const float*)d_in[3];
  const float* wc4 = (const float*)d_in[4];
  const float* wc5 = (const float*)d_in[5];
  const float* wf1 = (const float*)d_in[6];
  const float* wf2 = (const float*)d_in[7];
  const float* wf3 = (const float*)d_in[8];
  float* out = (float*)d_out;
  float* ws = (float*)d_ws;
  int* iws = (int*)((char*)d_ws + FLOAT_TOTAL * sizeof(float));
  if (ws_size < WS_NEED) return;  // ~86 MB needed

  // init: zero state + counters/flags; ones/eights/out via fill kernel
  hipMemsetAsync(ws, 0, ZEND * sizeof(float), stream);
  hipMemsetAsync(iws + I_CNT, 0, (64 + 8) * sizeof(int), stream);
  k_init_fill<<<512, 256, 0, stream>>>(ws, out);
  k_encode<<<N_IN / 256, 256, 0, stream>>>(input, iws, out);
  for (int d = 1; d <= 15; ++d)
    k_diag<<<DIAG_BLOCKS, 256, 0, stream>>>(d, wc1, wc2, wc3, wc4, wc5, wf1, wf2, wf3, out, ws,
                                            iws);
}

// Round 5
// 123.536 us; speedup vs baseline: 5.0290x; 1.0349x over previous
//
#include <hip/hip_runtime.h>
#include <cstddef>

#define B 8

constexpr float DM = 0.95122942450071400910f; // exp(-1/20) in f32
constexpr float DS = 0.81873075307798185867f; // exp(-1/5) in f32

constexpr int N_IN = B * 3 * 32 * 32;     // 24576
constexpr int N_L1 = B * 64 * 32 * 32;    // 524288
constexpr int N_L2 = B * 128 * 32 * 32;   // 1048576
constexpr int N_P1 = B * 128 * 16 * 16;   // 262144
constexpr int N_L3 = B * 256 * 16 * 16;   // 524288
constexpr int N_P2 = B * 256 * 8 * 8;     // 131072
constexpr int N_L4 = B * 512 * 8 * 8;     // 262144
constexpr int N_L5 = B * 256 * 8 * 8;     // 131072
constexpr int N_F1 = B * 1024;            // 8192
constexpr int N_F2 = B * 512;             // 4096

// ---- float workspace layout ----
// zeros
constexpr size_t O_UM1 = 0;
constexpr size_t O_US1 = O_UM1 + N_L1;
constexpr size_t O_UM2 = O_US1 + N_L1;
constexpr size_t O_US2 = O_UM2 + N_L2;
constexpr size_t O_P1E = O_US2 + N_L2;
constexpr size_t O_UM3 = O_P1E + N_L2;
constexpr size_t O_US3 = O_UM3 + N_L3;
constexpr size_t O_P2E = O_US3 + N_L3;
constexpr size_t O_UM4 = O_P2E + N_L3;
constexpr size_t O_US4 = O_UM4 + N_L4;
constexpr size_t O_UM5 = O_US4 + N_L4;
constexpr size_t O_US5 = O_UM5 + N_L5;
constexpr size_t O_UMF1 = O_US5 + N_L5;
constexpr size_t O_USF1 = O_UMF1 + N_F1;
constexpr size_t O_UMF2 = O_USF1 + N_F1;
constexpr size_t O_USF2 = O_UMF2 + N_F2;
constexpr size_t ZEND = O_USF2 + N_F2;
// ones (sav)
constexpr size_t O_SAV1 = ZEND;
constexpr size_t O_SAV2 = O_SAV1 + N_L1;
constexpr size_t O_SAV3 = O_SAV2 + N_L2;
constexpr size_t O_SAV4 = O_SAV3 + N_L3;
constexpr size_t O_SAV5 = O_SAV4 + N_L4;
constexpr size_t O_SAVF1 = O_SAV5 + N_L5;
constexpr size_t O_SAVF2 = O_SAVF1 + N_F1;
constexpr size_t OEND = O_SAVF2 + N_F2;
// eights (latency maps)
constexpr size_t O_P1L = OEND;
constexpr size_t O_P2L = O_P1L + N_L2;
constexpr size_t EEND = O_P2L + N_L3;
constexpr size_t FLOAT_TOTAL = EEND;
// ---- int workspace layout (per-step spike lists: 8 buffers each) ----
constexpr size_t I_L0 = 0;
constexpr size_t I_L1 = I_L0 + 8 * (size_t)N_IN;
constexpr size_t I_L2P = I_L1 + 8 * (size_t)N_L1;
constexpr size_t I_L3P = I_L2P + 8 * (size_t)N_P1;
constexpr size_t I_L4 = I_L3P + 8 * (size_t)N_P2;
constexpr size_t I_L5 = I_L4 + 8 * (size_t)N_L4;
constexpr size_t I_LF1 = I_L5 + 8 * (size_t)N_L5;
constexpr size_t I_LF2 = I_LF1 + 8 * (size_t)N_F1;
constexpr size_t I_CNT = I_LF2 + 8 * (size_t)N_F2;  // 64 counters [t][layer]
constexpr size_t I_FLAG = I_CNT + 64;               // 8 sticky activity flags
constexpr size_t INT_TOTAL = I_FLAG + 8;
constexpr size_t WS_NEED = FLOAT_TOTAL * sizeof(float) + INT_TOTAL * sizeof(int);

// block budget per layer cell (L = 1..7; fc3 provably a no-op, dropped)
constexpr int BUD[8] = {0, 512, 512, 512, 512, 256, 32, 16};
// cell (L,t) valid iff t in [L-1, 7]  (layer-delay bound)
constexpr bool cell_valid(int L, int d) { int t = d - L; return t >= L - 1 && t <= 7; }

__device__ __forceinline__ int ldcnt(const int* p) {
  return __hip_atomic_load(p, __ATOMIC_RELAXED, __HIP_MEMORY_SCOPE_AGENT);
}

// wave-aggregated compaction: 1 atomic per wave; optionally bumps sum_sp slot
__device__ __forceinline__ void wave_append(bool sp, int idx, int* cnt, int* list,
                                            float* sum_slot) {
  unsigned long long bal = __ballot(sp);
  if (bal == 0ull) return;
  int lane = threadIdx.x & 63;
  int leader = (int)__ffsll((unsigned long long)bal) - 1;
  int base = 0;
  if (lane == leader) {
    int n = __popcll(bal);
    base = atomicAdd(cnt, n);
    if (sum_slot) atomicAdd(sum_slot, (float)n);
  }
  base = __shfl(base, leader);
  if (sp) {
    int rank = __popcll(bal & ((1ull << lane) - 1ull));
    list[base + rank] = idx;
  }
}

// fused init: all float state (0 / 1 / 8 regions) via float4, counters+flags, out
__global__ void k_init(float* __restrict__ ws, float* __restrict__ out, int* __restrict__ iws) {
  const size_t i0 = (size_t)blockIdx.x * 256 + threadIdx.x;
  const size_t st = (size_t)gridDim.x * 256;
  constexpr size_t N4 = FLOAT_TOTAL / 4;  // all region sizes are multiples of 4
  for (size_t q = i0; q < N4; q += st) {
    size_t base = q * 4;
    float4 v;
    v.x = (base < ZEND) ? 0.0f : (base < OEND ? 1.0f : 8.0f);
    v.y = (base + 1 < ZEND) ? 0.0f : (base + 1 < OEND ? 1.0f : 8.0f);
    v.z = (base + 2 < ZEND) ? 0.0f : (base + 2 < OEND ? 1.0f : 8.0f);
    v.w = (base + 3 < ZEND) ? 0.0f : (base + 3 < OEND ? 1.0f : 8.0f);
    *reinterpret_cast<float4*>(ws + base) = v;
  }
  if (i0 < 72) iws[I_CNT + i0] = 0;
  if (i0 < 169) out[i0] = (i0 < 80) ? 8.0f : 0.0f;  // out_t starts at NUM_STEPS
}

// input encoding, all 8 steps in-register; emits per-step spike lists
__global__ void k_encode(const float* __restrict__ in, int* __restrict__ iws,
                         float* __restrict__ out) {
  int i = blockIdx.x * 256 + threadIdx.x;
  if (i >= N_IN) return;  // N_IN % 256 == 0: no partial waves
  int* cnt = iws + I_CNT;
  float x = in[i] * 0.2f;
  float u = 0.0f;
#pragma unroll
  for (int t = 0; t < 8; ++t) {
    u = DM * u + x;
    bool sp = (u - 1.0f > 0.0f);
    if (sp) u = 0.0f;
    wave_append(sp, i, cnt + t * 8 + 0, iws + I_L0 + (size_t)t * N_IN, out + 160);
  }
}

// conv cell: sticky-gate + LDS spike-scatter + NOSO update (+ pe/pl + latency min-pool) + compact
template <int CIN, int COUT, int H, int W, bool POOL>
__device__ void cell_conv(int lwg, int nwg, const int* __restrict__ list,
                          const int* __restrict__ cnt_in, int* __restrict__ flag,
                          const float* __restrict__ w, float* __restrict__ um,
                          float* __restrict__ us, float* __restrict__ sav,
                          float* __restrict__ pe, float* __restrict__ pl,
                          int* __restrict__ out_list, int* __restrict__ out_cnt,
                          float* __restrict__ sum_slot, float* s_acc, float* s_plb,
                          float* s_spb) {
  const int tid = threadIdx.x;
  const int S = ldcnt(cnt_in);
  if (*flag == 0) {
    if (S == 0) return;  // layer never touched and no input: provable no-op
    if (tid == 0 && lwg == 0) *flag = 1;
  }
  constexpr int HW = H * W;
  for (int plane = lwg; plane < B * COUT; plane += nwg) {
    const int b = plane / COUT, oc = plane % COUT;
    for (int p = tid; p < HW; p += 256) s_acc[p] = 0.0f;
    __syncthreads();
    for (int s = tid; s < S; s += 256) {
      int idx = list[s];
      int bs = idx / (CIN * HW);
      if (bs != b) continue;
      int r = idx - bs * (CIN * HW);
      int c = r / HW;
      int p = r - c * HW;
      int y = p / W, x = p - y * W;
      const float* wp = w + ((size_t)oc * CIN + c) * 25;
#pragma unroll
      for (int ki = 0; ki < 5; ++ki) {
        int oy = y + 2 - ki;
        if ((unsigned)oy < (unsigned)H) {
#pragma unroll
          for (int kj = 0; kj < 5; ++kj) {
            int ox = x + 2 - kj;
            if ((unsigned)ox < (unsigned)W) atomicAdd(&s_acc[oy * W + ox], wp[ki * 5 + kj]);
          }
        }
      }
    }
    __syncthreads();
    const size_t pb = (size_t)plane * HW;
    for (int p = tid; p < HW; p += 256) {
      size_t g = pb + p;
      float cv = s_acc[p];
      float m = DM * um[g] + cv;
      float s2 = DS * us[g] + cv;
      um[g] = m;
      us[g] = s2;
      float u = sav[g] * (m - s2);
      bool sp = (u - 1.0f > 0.0f);
      if (sp) sav[g] = 0.0f;
      if constexpr (POOL) {
        unsigned long long bal = __ballot(sp);
        if ((tid & 63) == 0 && bal) atomicAdd(sum_slot, (float)__popcll(bal));
        float pe_old = pe[g];
        float act = (m != 0.0f) ? 1.0f : 0.0f;
        float pe_new = pe_old + (((pe_old + act) != 0.0f) ? 1.0f : 0.0f);
        pe[g] = pe_new;
        float plv = pl[g];
        if (sp) {
          plv += pe_new - 7.0f;  // pl += sp * (pe - NUM_STEPS + 1)
          pl[g] = plv;
        }
        s_plb[p] = plv;
        s_spb[p] = sp ? 1.0f : 0.0f;
      } else {
        wave_append(sp, (int)g, out_cnt, out_list, sum_slot);
      }
    }
    if constexpr (POOL) {
      __syncthreads();
      constexpr int HP = H / 2, WP = W / 2;
      for (int q = tid; q < HP * WP; q += 256) {
        int py = q / WP, px = q - py * WP;
        int b2 = (2 * py) * W + 2 * px;
        float l0 = s_plb[b2], l1 = s_plb[b2 + 1], l2 = s_plb[b2 + W], l3 = s_plb[b2 + W + 1];
        int off = 0;
        float lm = l0;
        if (l1 < lm) { lm = l1; off = 1; }
        if (l2 < lm) { lm = l2; off = W; }
        if (l3 < lm) { lm = l3; off = W + 1; }
        bool psp = (s_spb[b2 + off] != 0.0f);
        wave_append(psp, plane * (HP * WP) + q, out_cnt, out_list, nullptr);
      }
    }
    __syncthreads();
  }
}

// fc cell: each thread owns exactly one output neuron (block budget == B*OUT/256)
template <int IN, int OUT>
__device__ void cell_fc(int lwg, const int* __restrict__ list, const int* __restrict__ cnt_in,
                        int* __restrict__ flag, const float* __restrict__ w,
                        float* __restrict__ um, float* __restrict__ us, float* __restrict__ sav,
                        int* __restrict__ out_list, int* __restrict__ out_cnt,
                        float* __restrict__ sum_slot) {
  const int tid = threadIdx.x;
  const int S = ldcnt(cnt_in);
  if (*flag == 0) {
    if (S == 0) return;
    if (tid == 0 && lwg == 0) *flag = 1;
  }
  int q = lwg * 256 + tid;
  int b = q / OUT, o = q - b * OUT;
  float acc = 0.0f;
  for (int s = 0; s < S; ++s) {
    int idx = list[s];
    int bs = idx / IN;
    if (bs == b) acc += w[(size_t)o * IN + (idx - bs * IN)];
  }
  float m = DM * um[q] + acc;
  float s2 = DS * us[q] + acc;
  um[q] = m;
  us[q] = s2;
  float u = sav[q] * (m - s2);
  bool sp = (u - 1.0f > 0.0f);
  if (sp) sav[q] = 0.0f;
  wave_append(sp, q, out_cnt, out_list, sum_slot);
}

// one dispatch per anti-diagonal d = L + t; grid sized exactly to valid cells
__global__ __launch_bounds__(256) void k_diag(int d, const float* __restrict__ wc1,
                                              const float* __restrict__ wc2,
                                              const float* __restrict__ wc3,
                                              const float* __restrict__ wc4,
                                              const float* __restrict__ wc5,
                                              const float* __restrict__ wf1,
                                              const float* __restrict__ wf2,
                                              float* __restrict__ out, float* __restrict__ ws,
                                              int* __restrict__ iws) {
  __shared__ float s_acc[1024];
  __shared__ float s_plb[1024];
  __shared__ float s_spb[1024];
  const int bid = blockIdx.x;
  int* cnt = iws + I_CNT;
  int* flags = iws + I_FLAG;
  // map bid -> (layer L, local wg, step t) over this diagonal's valid cells
  int off = 0, myL = 0, lwg = 0, t = 0;
  for (int L = 1; L <= 7; ++L) {
    if (!cell_valid(L, d)) continue;
    int bud = BUD[L];
    if (bid >= off && bid < off + bud && myL == 0) {
      myL = L;
      lwg = bid - off;
      t = d - L;
    }
    off += bud;
  }
  if (myL == 0) return;
  switch (myL) {
    case 1:
      cell_conv<3, 64, 32, 32, false>(lwg, BUD[1], iws + I_L0 + (size_t)t * N_IN,
                                      cnt + t * 8 + 0, flags + 0, wc1, ws + O_UM1, ws + O_US1,
                                      ws + O_SAV1, nullptr, nullptr,
                                      iws + I_L1 + (size_t)t * N_L1, cnt + t * 8 + 1, out + 161,
                                      s_acc, s_plb, s_spb);
      break;
    case 2:
      cell_conv<64, 128, 32, 32, true>(lwg, BUD[2], iws + I_L1 + (size_t)t * N_L1,
                                       cnt + t * 8 + 1, flags + 1, wc2, ws + O_UM2, ws + O_US2,
                                       ws + O_SAV2, ws + O_P1E, ws + O_P1L,
                                       iws + I_L2P + (size_t)t * N_P1, cnt + t * 8 + 2,
                                       out + 162, s_acc, s_plb, s_spb);
      break;
    case 3:
      cell_conv<128, 256, 16, 16, true>(lwg, BUD[3], iws + I_L2P + (size_t)t * N_P1,
                                        cnt + t * 8 + 2, flags + 2, wc3, ws + O_UM3, ws + O_US3,
                                        ws + O_SAV3, ws + O_P2E, ws + O_P2L,
                                        iws + I_L3P + (size_t)t * N_P2, cnt + t * 8 + 3,
                                        out + 163, s_acc, s_plb, s_spb);
      break;
    case 4:
      cell_conv<256, 512, 8, 8, false>(lwg, BUD[4], iws + I_L3P + (size_t)t * N_P2,
                                       cnt + t * 8 + 3, flags + 3, wc4, ws + O_UM4, ws + O_US4,
                                       ws + O_SAV4, nullptr, nullptr,
                                       iws + I_L4 + (size_t)t * N_L4, cnt + t * 8 + 4, out + 164,
                                       s_acc, s_plb, s_spb);
      break;
    case 5:
      cell_conv<512, 256, 8, 8, false>(lwg, BUD[5], iws + I_L4 + (size_t)t * N_L4,
                                       cnt + t * 8 + 4, flags + 4, wc5, ws + O_UM5, ws + O_US5,
                                       ws + O_SAV5, nullptr, nullptr,
                                       iws + I_L5 + (size_t)t * N_L5, cnt + t * 8 + 5, out + 165,
                                       s_acc, s_plb, s_spb);
      break;
    case 6:
      cell_fc<16384, 1024>(lwg, iws + I_L5 + (size_t)t * N_L5, cnt + t * 8 + 5, flags + 5, wf1,
                           ws + O_UMF1, ws + O_USF1, ws + O_SAVF1,
                           iws + I_LF1 + (size_t)t * N_F1, cnt + t * 8 + 6, out + 166);
      break;
    default:
      cell_fc<1024, 512>(lwg, iws + I_LF1 + (size_t)t * N_F1, cnt + t * 8 + 6, flags + 6, wf2,
                         ws + O_UMF2, ws + O_USF2, ws + O_SAVF2,
                         iws + I_LF2 + (size_t)t * N_F2, cnt + t * 8 + 7, out + 167);
      break;
  }
}

extern "C" void kernel_launch(void* const* d_in, const int* in_sizes, int n_in, void* d_out,
                              int out_size, void* d_ws, size_t ws_size, hipStream_t stream) {
  const float* input = (const float*)d_in[0];
  const float* wc1 = (const float*)d_in[1];
  const float* wc2 = (const float*)d_in[2];
  const float* wc3 = (const float*)d_in[3];
  const float* wc4 = (const float*)d_in[4];
  const float* wc5 = (const float*)d_in[5];
  const float* wf1 = (const float*)d_in[6];
  const float* wf2 = (const float*)d_in[7];
  float* out = (float*)d_out;
  float* ws = (float*)d_ws;
  int* iws = (int*)((char*)d_ws + FLOAT_TOTAL * sizeof(float));
  if (ws_size < WS_NEED) return;  // ~86 MB needed

  k_init<<<1024, 256, 0, stream>>>(ws, out, iws);
  k_encode<<<N_IN / 256, 256, 0, stream>>>(input, iws, out);
  for (int d = 1; d <= 14; ++d) {
    int grid = 0;
    for (int L = 1; L <= 7; ++L)
      if (cell_valid(L, d)) grid += BUD[L];
    k_diag<<<grid, 256, 0, stream>>>(d, wc1, wc2, wc3, wc4, wc5, wf1, wf2, out, ws, iws);
  }
}

// Round 6
// 114.524 us; speedup vs baseline: 5.4247x; 1.0787x over previous
//
#include <hip/hip_runtime.h>
#include <cstddef>

#define B 8

constexpr float DM = 0.95122942450071400910f; // exp(-1/20) in f32
constexpr float DS = 0.81873075307798185867f; // exp(-1/5) in f32

constexpr int N_IN = B * 3 * 32 * 32;     // 24576
constexpr int N_L1 = B * 64 * 32 * 32;    // 524288
constexpr int N_P1 = B * 128 * 16 * 16;   // 262144
constexpr int N_P2 = B * 256 * 8 * 8;     // 131072
constexpr int N_L4 = B * 512 * 8 * 8;     // 262144
constexpr int N_L5 = B * 256 * 8 * 8;     // 131072
constexpr int N_F1 = B * 1024;            // 8192
constexpr int N_F2 = B * 512;             // 4096

// ---- int workspace layout: per-step spike lists only (no float state at all) ----
constexpr size_t I_L0 = 0;
constexpr size_t I_L1 = I_L0 + 8 * (size_t)N_IN;
constexpr size_t I_P2 = I_L1 + 8 * (size_t)N_L1;
constexpr size_t I_P3 = I_P2 + 8 * (size_t)N_P1;
constexpr size_t I_L4 = I_P3 + 8 * (size_t)N_P2;
constexpr size_t I_L5 = I_L4 + 8 * (size_t)N_L4;
constexpr size_t I_F1 = I_L5 + 8 * (size_t)N_L5;
constexpr size_t I_F2 = I_F1 + 8 * (size_t)N_F1;
constexpr size_t I_CNT = I_F2 + 8 * (size_t)N_F2;  // 64 counters: cnt[t*8 + layer]
constexpr size_t INT_TOTAL = I_CNT + 64;
constexpr size_t WS_NEED = INT_TOTAL * sizeof(int);  // ~43 MB

__device__ __forceinline__ int ldcnt(const int* p) {
  return __hip_atomic_load(p, __ATOMIC_RELAXED, __HIP_MEMORY_SCOPE_AGENT);
}

// wave-aggregated compaction: 1 atomic per wave; optionally bumps sum_sp slot
__device__ __forceinline__ void wave_append(bool sp, int idx, int* cnt, int* list,
                                            float* sum_slot) {
  unsigned long long bal = __ballot(sp);
  if (bal == 0ull) return;
  int lane = threadIdx.x & 63;
  int leader = (int)__ffsll((unsigned long long)bal) - 1;
  int base = 0;
  if (lane == leader) {
    int n = __popcll(bal);
    base = atomicAdd(cnt, n);
    if (sum_slot) atomicAdd(sum_slot, (float)n);
  }
  base = __shfl(base, leader);
  if (sp) {
    int rank = __popcll(bal & ((1ull << lane) - 1ull));
    list[base + rank] = idx;
  }
}

// tiny init: 64 spike counters + out tail (sum_sp slots); out_t/out_u written by fc3
__global__ void k_init(float* __restrict__ out, int* __restrict__ cnt) {
  int i = threadIdx.x;
  if (i < 64) cnt[i] = 0;
  if (i < 169) out[i] = (i < 80) ? 8.0f : 0.0f;
}

// input encoding, all 8 steps in-register; emits per-step spike lists
__global__ void k_encode(const float* __restrict__ in, int* __restrict__ iws,
                         float* __restrict__ out) {
  int i = blockIdx.x * 256 + threadIdx.x;  // N_IN % 256 == 0: all waves full
  int* cnt = iws + I_CNT;
  float x = in[i] * 0.2f;
  float u = 0.0f;
#pragma unroll
  for (int t = 0; t < 8; ++t) {
    u = DM * u + x;
    bool sp = (u - 1.0f > 0.0f);
    if (sp) u = 0.0f;
    wave_append(sp, i, cnt + t * 8 + 0, iws + I_L0 + (size_t)t * N_IN, out + 160);
  }
}

// one kernel per conv layer: WG owns one (b,oc) plane for ALL timesteps.
// State (um/us/sav + pe/pl) lives in registers across the t-loop; LDS only for
// the per-step scatter accumulator and the 2x2 latency-pool exchange.
template <int CIN, int COUT, int H, int W, bool POOL>
__global__ __launch_bounds__(256) void k_conv_seq(const float* __restrict__ w,
                                                  int* __restrict__ cnt, int in_ci, int out_ci,
                                                  const int* __restrict__ in_list0,
                                                  int in_stride, int* __restrict__ out_list0,
                                                  int out_stride, float* __restrict__ sum_slot) {
  constexpr int HW = H * W;
  constexpr int PPT = (HW + 255) / 256;
  const int tid = threadIdx.x;
  const int plane = blockIdx.x;
  const int b = plane / COUT, oc = plane % COUT;
  float um[PPT], us[PPT], sav[PPT], pe[PPT], pl[PPT];
#pragma unroll
  for (int k = 0; k < PPT; ++k) {
    um[k] = 0.0f; us[k] = 0.0f; sav[k] = 1.0f; pe[k] = 0.0f; pl[k] = 8.0f;
  }
  __shared__ float s_acc[HW];
  __shared__ float s_plb[POOL ? HW : 4];
  __shared__ float s_spb[POOL ? HW : 4];
  bool active = false;
  for (int t = 0; t < 8; ++t) {
    const int S = ldcnt(cnt + t * 8 + in_ci);
    if (!active && S == 0) continue;  // exact: zero state + no input is a fixed point
    active = true;
    for (int p = tid; p < HW; p += 256) s_acc[p] = 0.0f;
    __syncthreads();
    const int* list = in_list0 + (size_t)t * in_stride;
    for (int s = tid; s < S; s += 256) {
      int idx = list[s];
      int bs = idx / (CIN * HW);
      if (bs != b) continue;
      int r = idx - bs * (CIN * HW);
      int c = r / HW;
      int p = r - c * HW;
      int y = p / W, x = p - y * W;
      const float* wp = w + ((size_t)oc * CIN + c) * 25;
#pragma unroll
      for (int ki = 0; ki < 5; ++ki) {
        int oy = y + 2 - ki;
        if ((unsigned)oy < (unsigned)H) {
#pragma unroll
          for (int kj = 0; kj < 5; ++kj) {
            int ox = x + 2 - kj;
            if ((unsigned)ox < (unsigned)W) atomicAdd(&s_acc[oy * W + ox], wp[ki * 5 + kj]);
          }
        }
      }
    }
    __syncthreads();
    int* out_list = out_list0 + (size_t)t * out_stride;
    int* out_cnt = cnt + t * 8 + out_ci;
#pragma unroll
    for (int k = 0; k < PPT; ++k) {
      int p = tid + k * 256;
      bool lane_ok = (p < HW);
      float cv = lane_ok ? s_acc[p] : 0.0f;
      float m = DM * um[k] + cv;
      float s2 = DS * us[k] + cv;
      um[k] = m;
      us[k] = s2;
      float u = sav[k] * (m - s2);
      bool sp = lane_ok && (u - 1.0f > 0.0f);
      if (sp) sav[k] = 0.0f;
      if constexpr (POOL) {
        unsigned long long bal = __ballot(sp);
        if ((tid & 63) == 0 && bal) atomicAdd(sum_slot, (float)__popcll(bal));
        if (lane_ok) {
          float act = (m != 0.0f) ? 1.0f : 0.0f;
          float pen = pe[k] + (((pe[k] + act) != 0.0f) ? 1.0f : 0.0f);
          pe[k] = pen;
          if (sp) pl[k] += pen - 7.0f;  // pl += sp * (pe - NUM_STEPS + 1)
          s_plb[p] = pl[k];
          s_spb[p] = sp ? 1.0f : 0.0f;
        }
      } else {
        wave_append(sp, plane * HW + p, out_cnt, out_list, sum_slot);
      }
    }
    if constexpr (POOL) {
      __syncthreads();
      constexpr int HP = H / 2, WP = W / 2;
      for (int q = tid; q < HP * WP; q += 256) {
        int py = q / WP, px = q - py * WP;
        int base = (2 * py) * W + 2 * px;
        float l0 = s_plb[base], l1 = s_plb[base + 1], l2 = s_plb[base + W],
              l3 = s_plb[base + W + 1];
        int off = 0;
        float lm = l0;
        if (l1 < lm) { lm = l1; off = 1; }
        if (l2 < lm) { lm = l2; off = W; }
        if (l3 < lm) { lm = l3; off = W + 1; }
        bool psp = (s_spb[base + off] != 0.0f);
        wave_append(psp, plane * (HP * WP) + q, out_cnt, out_list, nullptr);
      }
    }
    __syncthreads();
  }
}

// one kernel per fc layer: thread owns one output neuron for all timesteps
template <int IN, int OUT>
__global__ __launch_bounds__(256) void k_fc_seq(const float* __restrict__ w,
                                                int* __restrict__ cnt, int in_ci, int out_ci,
                                                const int* __restrict__ in_list0, int in_stride,
                                                int* __restrict__ out_list0, int out_stride,
                                                float* __restrict__ sum_slot) {
  const int q = blockIdx.x * 256 + threadIdx.x;
  const int b = q / OUT, o = q - b * OUT;
  float um = 0.0f, us = 0.0f, sav = 1.0f;
  bool active = false;
  for (int t = 0; t < 8; ++t) {
    const int S = ldcnt(cnt + t * 8 + in_ci);
    if (!active && S == 0) continue;
    active = true;
    const int* list = in_list0 + (size_t)t * in_stride;
    float acc = 0.0f;
    for (int s = 0; s < S; ++s) {
      int idx = list[s];
      int bs = idx / IN;
      if (bs == b) acc += w[(size_t)o * IN + (idx - bs * IN)];
    }
    float m = DM * um + acc;
    float s2 = DS * us + acc;
    um = m;
    us = s2;
    float u = sav * (m - s2);
    bool sp = (u - 1.0f > 0.0f);
    if (sp) sav = 0.0f;
    wave_append(sp, q, cnt + t * 8 + out_ci, out_list0 + (size_t)t * out_stride, sum_slot);
  }
}

// final FC (512->10) + te/out_t/out_u epilogue; out_t/out_u accumulated in registers
__global__ void k_fc3_seq(const float* __restrict__ w, int* __restrict__ cnt, int in_ci,
                          const int* __restrict__ in_list0, int in_stride,
                          float* __restrict__ out) {
  const int tid = threadIdx.x;  // 128 threads (2 waves)
  const bool lane_ok = (tid < 80);
  const int b = tid / 10, o = tid - b * 10;
  float um = 0.0f, us = 0.0f, sav = 1.0f, te = 0.0f, ot = 8.0f, ou = 0.0f;
  bool active = false;
  for (int t = 0; t < 8; ++t) {
    const int S = ldcnt(cnt + t * 8 + in_ci);
    if (!active && S == 0) continue;
    active = true;
    const int* list = in_list0 + (size_t)t * in_stride;
    float acc = 0.0f;
    if (lane_ok) {
      for (int s = 0; s < S; ++s) {
        int idx = list[s];
        int bs = idx >> 9;
        if (bs == b) acc += w[o * 512 + (idx & 511)];
      }
    }
    float m = DM * um + acc;
    float s2 = DS * us + acc;
    um = m;
    us = s2;
    float u = sav * (m - s2);
    bool sp = lane_ok && (u - 1.0f > 0.0f);
    if (sp) sav = 0.0f;
    float act = (u != 0.0f) ? 1.0f : 0.0f;
    te = te + (((te + act) != 0.0f) ? 1.0f : 0.0f);
    if (sp) {
      ot += te - 8.0f;  // out_t (dodt forward)
      ou += u;          // out_u
    }
    unsigned long long bal = __ballot(sp);
    if ((tid & 63) == 0 && bal) atomicAdd(&out[168], (float)__popcll(bal));
  }
  if (lane_ok) {
    out[tid] = ot;
    out[80 + tid] = ou;
  }
}

extern "C" void kernel_launch(void* const* d_in, const int* in_sizes, int n_in, void* d_out,
                              int out_size, void* d_ws, size_t ws_size, hipStream_t stream) {
  const float* input = (const float*)d_in[0];
  const float* wc1 = (const float*)d_in[1];
  const float* wc2 = (const float*)d_in[2];
  const float* wc3 = (const float*)d_in[3];
  const float* wc4 = (const float*)d_in[4];
  const float* wc5 = (const float*)d_in[5];
  const float* wf1 = (const float*)d_in[6];
  const float* wf2 = (const float*)d_in[7];
  const float* wf3 = (const float*)d_in[8];
  float* out = (float*)d_out;
  int* iws = (int*)d_ws;
  int* cnt = iws + I_CNT;
  if (ws_size < WS_NEED) return;  // ~43 MB needed

  k_init<<<1, 256, 0, stream>>>(out, cnt);
  k_encode<<<N_IN / 256, 256, 0, stream>>>(input, iws, out);
  k_conv_seq<3, 64, 32, 32, false><<<B * 64, 256, 0, stream>>>(
      wc1, cnt, 0, 1, iws + I_L0, N_IN, iws + I_L1, N_L1, out + 161);
  k_conv_seq<64, 128, 32, 32, true><<<B * 128, 256, 0, stream>>>(
      wc2, cnt, 1, 2, iws + I_L1, N_L1, iws + I_P2, N_P1, out + 162);
  k_conv_seq<128, 256, 16, 16, true><<<B * 256, 256, 0, stream>>>(
      wc3, cnt, 2, 3, iws + I_P2, N_P1, iws + I_P3, N_P2, out + 163);
  k_conv_seq<256, 512, 8, 8, false><<<B * 512, 256, 0, stream>>>(
      wc4, cnt, 3, 4, iws + I_P3, N_P2, iws + I_L4, N_L4, out + 164);
  k_conv_seq<512, 256, 8, 8, false><<<B * 256, 256, 0, stream>>>(
      wc5, cnt, 4, 5, iws + I_L4, N_L4, iws + I_L5, N_L5, out + 165);
  k_fc_seq<16384, 1024><<<B * 1024 / 256, 256, 0, stream>>>(
      wf1, cnt, 5, 6, iws + I_L5, N_L5, iws + I_F1, N_F1, out + 166);
  k_fc_seq<1024, 512><<<B * 512 / 256, 256, 0, stream>>>(
      wf2, cnt, 6, 7, iws + I_F1, N_F1, iws + I_F2, N_F2, out + 167);
  k_fc3_seq<<<1, 128, 0, stream>>>(wf3, cnt, 7, iws + I_F2, N_F2, out);
}

// Round 7
// 99.880 us; speedup vs baseline: 6.2201x; 1.1466x over previous
//
#include <hip/hip_runtime.h>
#include <cstddef>

#define B 8

constexpr float DM = 0.95122942450071400910f; // exp(-1/20) in f32
constexpr float DS = 0.81873075307798185867f; // exp(-1/5) in f32

constexpr int N_IN = B * 3 * 32 * 32;  // 24576

// bucket strides (elements per (t,b) bucket) = neurons per batch
constexpr int BS_L0 = 3 * 32 * 32;    // 3072
constexpr int BS_L1 = 64 * 32 * 32;   // 65536
constexpr int BS_P1 = 128 * 16 * 16;  // 32768
constexpr int BS_P2 = 256 * 8 * 8;    // 16384
constexpr int BS_L4 = 512 * 8 * 8;    // 32768
constexpr int BS_L5 = 256 * 8 * 8;    // 16384
constexpr int BS_F1 = 1024;
constexpr int BS_F2 = 512;

// ---- int workspace layout: per-(t,b) bucketed spike lists ----
constexpr size_t I_L0 = 0;
constexpr size_t I_L1 = I_L0 + 8 * (size_t)B * BS_L0;
constexpr size_t I_P1 = I_L1 + 8 * (size_t)B * BS_L1;
constexpr size_t I_P2 = I_P1 + 8 * (size_t)B * BS_P1;
constexpr size_t I_L4 = I_P2 + 8 * (size_t)B * BS_P2;
constexpr size_t I_L5 = I_L4 + 8 * (size_t)B * BS_L4;
constexpr size_t I_F1 = I_L5 + 8 * (size_t)B * BS_L5;
constexpr size_t I_F2 = I_F1 + 8 * (size_t)B * BS_F1;
constexpr size_t I_CNT = I_F2 + 8 * (size_t)B * BS_F2;  // 512 counters: [(t*8+ci)*8+b]
constexpr size_t INT_TOTAL = I_CNT + 512;
constexpr size_t WS_NEED = INT_TOTAL * sizeof(int);  // ~43 MB

constexpr int ilog2(int n) { int l = 0; while (n > 1) { n >>= 1; ++l; } return l; }

__device__ __forceinline__ int ldcnt(const int* p) {
  return __hip_atomic_load(p, __ATOMIC_RELAXED, __HIP_MEMORY_SCOPE_AGENT);
}

// wave-aggregated compaction: 1 atomic per wave; optionally bumps sum_sp slot
__device__ __forceinline__ void wave_append(bool sp, int idx, int* cnt, int* list,
                                            float* sum_slot) {
  unsigned long long bal = __ballot(sp);
  if (bal == 0ull) return;
  int lane = threadIdx.x & 63;
  int leader = (int)__ffsll((unsigned long long)bal) - 1;
  int base = 0;
  if (lane == leader) {
    int n = __popcll(bal);
    base = atomicAdd(cnt, n);
    if (sum_slot) atomicAdd(sum_slot, (float)n);
  }
  base = __shfl(base, leader);
  if (sp) {
    int rank = __popcll(bal & ((1ull << lane) - 1ull));
    list[base + rank] = idx;
  }
}

// tiny init: 512 spike counters + out (out_t=8, rest 0)
__global__ void k_init(float* __restrict__ out, int* __restrict__ cnt) {
  int i = threadIdx.x;
  if (i < 512) cnt[i] = 0;
  if (i < 169) out[i] = (i < 80) ? 8.0f : 0.0f;
}

// input encoding, all 8 steps in-register; emits per-(t,b) bucketed spike lists
// (waves never cross a batch boundary: 3072 % 64 == 0)
__global__ void k_encode(const float* __restrict__ in, int* __restrict__ iws,
                         float* __restrict__ out) {
  int i = blockIdx.x * 256 + threadIdx.x;
  int b = i / BS_L0;
  int loc = i - b * BS_L0;
  int* cnt = iws + I_CNT;
  float x = in[i] * 0.2f;
  float u = 0.0f;
#pragma unroll
  for (int t = 0; t < 8; ++t) {
    u = DM * u + x;
    bool sp = (u - 1.0f > 0.0f);
    if (sp) u = 0.0f;
    wave_append(sp, loc, cnt + (t * 8 + 0) * 8 + b, iws + I_L0 + ((size_t)t * B + b) * BS_L0,
                out + 160);
  }
}

// one kernel per conv layer: WG owns one (b,oc) plane across ALL timesteps.
// State in registers; LDS only for scatter accumulator + pool exchange.
// Scatter uses batched wr[25] weight preload (independent loads, one latency).
template <int CIN, int COUT, int H, int W, bool POOL>
__global__ __launch_bounds__(256) void k_conv_seq(const float* __restrict__ w,
                                                  int* __restrict__ cnt, int in_ci, int out_ci,
                                                  const int* __restrict__ in_list0,
                                                  int in_bstride, int* __restrict__ out_list0,
                                                  int out_bstride, float* __restrict__ sum_slot) {
  constexpr int HW = H * W;
  constexpr int HWlog = ilog2(HW);
  constexpr int Wlog = ilog2(W);
  constexpr int PPT = (HW + 255) / 256;
  const int tid = threadIdx.x;
  const int plane = blockIdx.x;
  const int b = plane >> ilog2(COUT);
  const int oc = plane & (COUT - 1);
  float um[PPT], us[PPT], sav[PPT], pe[PPT], pl[PPT];
#pragma unroll
  for (int k = 0; k < PPT; ++k) {
    um[k] = 0.0f; us[k] = 0.0f; sav[k] = 1.0f; pe[k] = 0.0f; pl[k] = 8.0f;
  }
  __shared__ float s_acc[HW];
  __shared__ float s_plb[POOL ? HW : 4];
  __shared__ float s_spb[POOL ? HW : 4];
  bool active = false;
  for (int t = 0; t < 8; ++t) {
    const int S = ldcnt(cnt + (t * 8 + in_ci) * 8 + b);
    if (!active && S == 0) continue;  // exact: zero state + no input is a fixed point
    active = true;
    for (int p = tid; p < HW; p += 256) s_acc[p] = 0.0f;
    __syncthreads();
    const int* list = in_list0 + ((size_t)t * B + b) * in_bstride;
    for (int s = tid; s < S; s += 256) {
      int loc = list[s];
      int c = loc >> HWlog;
      int p = loc & (HW - 1);
      int y = p >> Wlog, x = p & (W - 1);
      const float* wp = w + ((size_t)oc * CIN + c) * 25;
      float wr[25];
#pragma unroll
      for (int k = 0; k < 25; ++k) wr[k] = wp[k];
#pragma unroll
      for (int ki = 0; ki < 5; ++ki) {
        int oy = y + 2 - ki;
        if ((unsigned)oy < (unsigned)H) {
#pragma unroll
          for (int kj = 0; kj < 5; ++kj) {
            int ox = x + 2 - kj;
            if ((unsigned)ox < (unsigned)W) atomicAdd(&s_acc[oy * W + ox], wr[ki * 5 + kj]);
          }
        }
      }
    }
    __syncthreads();
    int* out_list = out_list0 + ((size_t)t * B + b) * out_bstride;
    int* out_cnt = cnt + (t * 8 + out_ci) * 8 + b;
#pragma unroll
    for (int k = 0; k < PPT; ++k) {
      int p = tid + k * 256;
      bool lane_ok = (p < HW);
      float cv = lane_ok ? s_acc[p] : 0.0f;
      float m = DM * um[k] + cv;
      float s2 = DS * us[k] + cv;
      um[k] = m;
      us[k] = s2;
      float u = sav[k] * (m - s2);
      bool sp = lane_ok && (u - 1.0f > 0.0f);
      if (sp) sav[k] = 0.0f;
      if constexpr (POOL) {
        unsigned long long bal = __ballot(sp);
        if ((tid & 63) == 0 && bal) atomicAdd(sum_slot, (float)__popcll(bal));
        if (lane_ok) {
          float act = (m != 0.0f) ? 1.0f : 0.0f;
          float pen = pe[k] + (((pe[k] + act) != 0.0f) ? 1.0f : 0.0f);
          pe[k] = pen;
          if (sp) pl[k] += pen - 7.0f;  // pl += sp * (pe - NUM_STEPS + 1)
          s_plb[p] = pl[k];
          s_spb[p] = sp ? 1.0f : 0.0f;
        }
      } else {
        wave_append(sp, (oc << HWlog) + p, out_cnt, out_list, sum_slot);
      }
    }
    if constexpr (POOL) {
      __syncthreads();
      constexpr int HP = H / 2, WP = W / 2;
      for (int q = tid; q < HP * WP; q += 256) {
        int py = q / WP, px = q - py * WP;
        int base = (2 * py) * W + 2 * px;
        float l0 = s_plb[base], l1 = s_plb[base + 1], l2 = s_plb[base + W],
              l3 = s_plb[base + W + 1];
        int off = 0;
        float lm = l0;
        if (l1 < lm) { lm = l1; off = 1; }
        if (l2 < lm) { lm = l2; off = W; }
        if (l3 < lm) { lm = l3; off = W + 1; }
        bool psp = (s_spb[base + off] != 0.0f);
        wave_append(psp, oc * (HP * WP) + q, out_cnt, out_list, nullptr);
      }
    }
    __syncthreads();
  }
}

// one kernel per fc layer: thread owns one output neuron for all timesteps
template <int IN, int OUT>
__global__ __launch_bounds__(256) void k_fc_seq(const float* __restrict__ w,
                                                int* __restrict__ cnt, int in_ci, int out_ci,
                                                const int* __restrict__ in_list0, int in_bstride,
                                                int* __restrict__ out_list0, int out_bstride,
                                                float* __restrict__ sum_slot) {
  const int q = blockIdx.x * 256 + threadIdx.x;
  const int b = q >> ilog2(OUT);
  const int o = q & (OUT - 1);
  float um = 0.0f, us = 0.0f, sav = 1.0f;
  bool active = false;
  for (int t = 0; t < 8; ++t) {
    const int S = ldcnt(cnt + (t * 8 + in_ci) * 8 + b);
    if (!active && S == 0) continue;
    active = true;
    const int* list = in_list0 + ((size_t)t * B + b) * in_bstride;
    float acc = 0.0f;
    for (int s = 0; s < S; ++s) acc += w[(size_t)o * IN + list[s]];
    float m = DM * um + acc;
    float s2 = DS * us + acc;
    um = m;
    us = s2;
    float u = sav * (m - s2);
    bool sp = (u - 1.0f > 0.0f);
    if (sp) sav = 0.0f;
    wave_append(sp, o, cnt + (t * 8 + out_ci) * 8 + b,
                out_list0 + ((size_t)t * B + b) * out_bstride, sum_slot);
  }
}

// final FC (512->10) + te/out_t/out_u epilogue; lanes span batches -> wave-collective gate
__global__ void k_fc3_seq(const float* __restrict__ w, int* __restrict__ cnt, int in_ci,
                          const int* __restrict__ in_list0, int in_bstride,
                          float* __restrict__ out) {
  const int tid = threadIdx.x;  // 128 threads (2 waves)
  const bool lane_ok = (tid < 80);
  const int b = lane_ok ? tid / 10 : 0;
  const int o = lane_ok ? tid - b * 10 : 0;
  float um = 0.0f, us = 0.0f, sav = 1.0f, te = 0.0f, ot = 8.0f, ou = 0.0f;
  bool active = false;
  for (int t = 0; t < 8; ++t) {
    const int S = lane_ok ? ldcnt(cnt + (t * 8 + in_ci) * 8 + b) : 0;
    if (!active && !__any(S > 0)) continue;  // wave-collective gate (inactive lanes are exact)
    active = true;
    const int* list = in_list0 + ((size_t)t * B + b) * in_bstride;
    float acc = 0.0f;
    for (int s = 0; s < S; ++s) acc += w[o * 512 + list[s]];
    float m = DM * um + acc;
    float s2 = DS * us + acc;
    um = m;
    us = s2;
    float u = sav * (m - s2);
    bool sp = lane_ok && (u - 1.0f > 0.0f);
    if (sp) sav = 0.0f;
    float act = (u != 0.0f) ? 1.0f : 0.0f;
    te = te + (((te + act) != 0.0f) ? 1.0f : 0.0f);
    if (sp) {
      ot += te - 8.0f;  // out_t (dodt forward)
      ou += u;          // out_u
    }
    unsigned long long bal = __ballot(sp);
    if ((tid & 63) == 0 && bal) atomicAdd(&out[168], (float)__popcll(bal));
  }
  if (lane_ok) {
    out[tid] = ot;
    out[80 + tid] = ou;
  }
}

extern "C" void kernel_launch(void* const* d_in, const int* in_sizes, int n_in, void* d_out,
                              int out_size, void* d_ws, size_t ws_size, hipStream_t stream) {
  const float* input = (const float*)d_in[0];
  const float* wc1 = (const float*)d_in[1];
  const float* wc2 = (const float*)d_in[2];
  const float* wc3 = (const float*)d_in[3];
  const float* wc4 = (const float*)d_in[4];
  const float* wc5 = (const float*)d_in[5];
  const float* wf1 = (const float*)d_in[6];
  const float* wf2 = (const float*)d_in[7];
  const float* wf3 = (const float*)d_in[8];
  float* out = (float*)d_out;
  int* iws = (int*)d_ws;
  int* cnt = iws + I_CNT;
  if (ws_size < WS_NEED) return;  // ~43 MB needed

  k_init<<<1, 512, 0, stream>>>(out, cnt);
  k_encode<<<N_IN / 256, 256, 0, stream>>>(input, iws, out);
  k_conv_seq<3, 64, 32, 32, false><<<B * 64, 256, 0, stream>>>(
      wc1, cnt, 0, 1, iws + I_L0, BS_L0, iws + I_L1, BS_L1, out + 161);
  k_conv_seq<64, 128, 32, 32, true><<<B * 128, 256, 0, stream>>>(
      wc2, cnt, 1, 2, iws + I_L1, BS_L1, iws + I_P1, BS_P1, out + 162);
  k_conv_seq<128, 256, 16, 16, true><<<B * 256, 256, 0, stream>>>(
      wc3, cnt, 2, 3, iws + I_P1, BS_P1, iws + I_P2, BS_P2, out + 163);
  k_conv_seq<256, 512, 8, 8, false><<<B * 512, 256, 0, stream>>>(
      wc4, cnt, 3, 4, iws + I_P2, BS_P2, iws + I_L4, BS_L4, out + 164);
  k_conv_seq<512, 256, 8, 8, false><<<B * 256, 256, 0, stream>>>(
      wc5, cnt, 4, 5, iws + I_L4, BS_L4, iws + I_L5, BS_L5, out + 165);
  k_fc_seq<16384, 1024><<<B * 1024 / 256, 256, 0, stream>>>(
      wf1, cnt, 5, 6, iws + I_L5, BS_L5, iws + I_F1, BS_F1, out + 166);
  k_fc_seq<1024, 512><<<B * 512 / 256, 256, 0, stream>>>(
      wf2, cnt, 6, 7, iws + I_F1, BS_F1, iws + I_F2, BS_F2, out + 167);
  k_fc3_seq<<<1, 128, 0, stream>>>(wf3, cnt, 7, iws + I_F2, BS_F2, out);
}

// Round 8
// 92.922 us; speedup vs baseline: 6.6858x; 1.0749x over previous
//
#include <hip/hip_runtime.h>
#include <cstddef>

#define B 8

constexpr float DM = 0.95122942450071400910f; // exp(-1/20) in f32
constexpr float DS = 0.81873075307798185867f; // exp(-1/5) in f32

constexpr int N_IN = B * 3 * 32 * 32;  // 24576

// bucket strides (elements per (t,b) bucket) = neurons per batch
constexpr int BS_L0 = 3 * 32 * 32;    // 3072
constexpr int BS_L1 = 64 * 32 * 32;   // 65536
constexpr int BS_P1 = 128 * 16 * 16;  // 32768
constexpr int BS_P2 = 256 * 8 * 8;    // 16384
constexpr int BS_L4 = 512 * 8 * 8;    // 32768
constexpr int BS_L5 = 256 * 8 * 8;    // 16384
constexpr int BS_F1 = 1024;
constexpr int BS_F2 = 512;

// ---- int workspace layout: per-(t,b) bucketed spike lists ----
constexpr size_t I_L0 = 0;
constexpr size_t I_L1 = I_L0 + 8 * (size_t)B * BS_L0;
constexpr size_t I_P1 = I_L1 + 8 * (size_t)B * BS_L1;
constexpr size_t I_P2 = I_P1 + 8 * (size_t)B * BS_P1;
constexpr size_t I_L4 = I_P2 + 8 * (size_t)B * BS_P2;
constexpr size_t I_L5 = I_L4 + 8 * (size_t)B * BS_L4;
constexpr size_t I_F1 = I_L5 + 8 * (size_t)B * BS_L5;
constexpr size_t I_F2 = I_F1 + 8 * (size_t)B * BS_F1;
constexpr size_t I_CNT = I_F2 + 8 * (size_t)B * BS_F2;  // 512 counters: [(t*8+ci)*8+b]
constexpr size_t I_SUMP = I_CNT + 512;                  // 16 floats: unpooled-count partials
constexpr size_t INT_TOTAL = I_SUMP + 16;
constexpr size_t WS_NEED = INT_TOTAL * sizeof(int);  // ~43 MB

constexpr int ilog2(int n) { int l = 0; while (n > 1) { n >>= 1; ++l; } return l; }

__device__ __forceinline__ int ldcnt(const int* p) {
  return __hip_atomic_load(p, __ATOMIC_RELAXED, __HIP_MEMORY_SCOPE_AGENT);
}

// stage spikes into a block-local LDS list: LDS atomics only (no global contention)
__device__ __forceinline__ void block_stage(bool sp, int idx, int* s_list, int* s_n) {
  unsigned long long bal = __ballot(sp);
  if (bal == 0ull) return;
  int lane = threadIdx.x & 63;
  int leader = (int)__ffsll((unsigned long long)bal) - 1;
  int base = 0;
  if (lane == leader) base = atomicAdd(s_n, __popcll(bal));
  base = __shfl(base, leader);
  if (sp) s_list[base + __popcll(bal & ((1ull << lane) - 1ull))] = idx;
}

// tiny init: 512 spike counters + 16 partial-sum floats (out fully written by fc3)
__global__ void k_init(int* __restrict__ cw) {
  int i = threadIdx.x;
  if (i < 528) cw[i] = 0;
}

// input encoding, all 8 steps in-register; block-staged per-(t,b) spike lists
__global__ void k_encode(const float* __restrict__ in, int* __restrict__ iws) {
  __shared__ int s_list[256];
  __shared__ int s_n, s_base;
  const int tid = threadIdx.x;
  int i = blockIdx.x * 256 + tid;  // 3072 % 256 == 0: block never crosses a batch
  int b = i / BS_L0;
  int loc = i - b * BS_L0;
  int* cnt = iws + I_CNT;
  float x = in[i] * 0.2f;
  float u = 0.0f;
  for (int t = 0; t < 8; ++t) {
    if (tid == 0) s_n = 0;
    __syncthreads();
    u = DM * u + x;
    bool sp = (u - 1.0f > 0.0f);
    if (sp) u = 0.0f;
    block_stage(sp, loc, s_list, &s_n);
    __syncthreads();
    if (tid == 0 && s_n > 0) s_base = atomicAdd(cnt + (t * 8 + 0) * 8 + b, s_n);
    __syncthreads();
    int* list = iws + I_L0 + ((size_t)t * B + b) * BS_L0;
    for (int j = tid; j < s_n; j += 256) list[s_base + j] = s_list[j];
    __syncthreads();
  }
}

// one kernel per conv layer: WG owns one (b,oc) plane across ALL timesteps.
// State in registers; LDS for scatter accumulator, pool exchange, and staged compaction.
template <int CIN, int COUT, int H, int W, bool POOL>
__global__ __launch_bounds__(256) void k_conv_seq(const float* __restrict__ w,
                                                  int* __restrict__ cnt, int in_ci, int out_ci,
                                                  const int* __restrict__ in_list0,
                                                  int in_bstride, int* __restrict__ out_list0,
                                                  int out_bstride, float* __restrict__ sump_layer) {
  constexpr int HW = H * W;
  constexpr int HWlog = ilog2(HW);
  constexpr int Wlog = ilog2(W);
  constexpr int PPT = (HW + 255) / 256;
  const int tid = threadIdx.x;
  const int plane = blockIdx.x;
  const int b = plane >> ilog2(COUT);
  const int oc = plane & (COUT - 1);
  float um[PPT], us[PPT], sav[PPT], pe[PPT], pl[PPT];
#pragma unroll
  for (int k = 0; k < PPT; ++k) {
    um[k] = 0.0f; us[k] = 0.0f; sav[k] = 1.0f; pe[k] = 0.0f; pl[k] = 8.0f;
  }
  __shared__ float s_acc[HW];
  __shared__ float s_plb[POOL ? HW : 4];
  __shared__ float s_spb[POOL ? HW : 4];
  __shared__ int s_list[HW];
  __shared__ int s_n, s_base, s_uc;
  int wcount = 0;  // per-wave-leader unpooled spike count (POOL layers)
  bool active = false;
  for (int t = 0; t < 8; ++t) {
    const int S = ldcnt(cnt + (t * 8 + in_ci) * 8 + b);
    if (!active && S == 0) continue;  // exact: zero state + no input is a fixed point
    active = true;
    for (int p = tid; p < HW; p += 256) s_acc[p] = 0.0f;
    if (tid == 0) s_n = 0;
    __syncthreads();
    const int* list = in_list0 + ((size_t)t * B + b) * in_bstride;
    for (int s = tid; s < S; s += 256) {
      int loc = list[s];
      int c = loc >> HWlog;
      int p = loc & (HW - 1);
      int y = p >> Wlog, x = p & (W - 1);
      const float* wp = w + ((size_t)oc * CIN + c) * 25;
      float wr[25];
#pragma unroll
      for (int k = 0; k < 25; ++k) wr[k] = wp[k];
#pragma unroll
      for (int ki = 0; ki < 5; ++ki) {
        int oy = y + 2 - ki;
        if ((unsigned)oy < (unsigned)H) {
#pragma unroll
          for (int kj = 0; kj < 5; ++kj) {
            int ox = x + 2 - kj;
            if ((unsigned)ox < (unsigned)W) atomicAdd(&s_acc[oy * W + ox], wr[ki * 5 + kj]);
          }
        }
      }
    }
    __syncthreads();
#pragma unroll
    for (int k = 0; k < PPT; ++k) {
      int p = tid + k * 256;
      bool lane_ok = (p < HW);
      float cv = lane_ok ? s_acc[p] : 0.0f;
      float m = DM * um[k] + cv;
      float s2 = DS * us[k] + cv;
      um[k] = m;
      us[k] = s2;
      float u = sav[k] * (m - s2);
      bool sp = lane_ok && (u - 1.0f > 0.0f);
      if (sp) sav[k] = 0.0f;
      if constexpr (POOL) {
        unsigned long long bal = __ballot(sp);
        if ((tid & 63) == 0) wcount += (int)__popcll(bal);
        if (lane_ok) {
          float act = (m != 0.0f) ? 1.0f : 0.0f;
          float pen = pe[k] + (((pe[k] + act) != 0.0f) ? 1.0f : 0.0f);
          pe[k] = pen;
          if (sp) pl[k] += pen - 7.0f;  // pl += sp * (pe - NUM_STEPS + 1)
          s_plb[p] = pl[k];
          s_spb[p] = sp ? 1.0f : 0.0f;
        }
      } else {
        block_stage(sp, (oc << HWlog) + p, s_list, &s_n);
      }
    }
    __syncthreads();
    if constexpr (POOL) {
      constexpr int HP = H / 2, WP = W / 2;
      for (int q = tid; q < HP * WP; q += 256) {
        int py = q / WP, px = q - py * WP;
        int base = (2 * py) * W + 2 * px;
        float l0 = s_plb[base], l1 = s_plb[base + 1], l2 = s_plb[base + W],
              l3 = s_plb[base + W + 1];
        int off = 0;
        float lm = l0;
        if (l1 < lm) { lm = l1; off = 1; }
        if (l2 < lm) { lm = l2; off = W; }
        if (l3 < lm) { lm = l3; off = W + 1; }
        bool psp = (s_spb[base + off] != 0.0f);
        block_stage(psp, oc * (HP * WP) + q, s_list, &s_n);
      }
      __syncthreads();
    }
    // flush staged spikes: ONE contended atomic per block per step + coalesced copy
    int* out_cnt = cnt + (t * 8 + out_ci) * 8 + b;
    if (tid == 0 && s_n > 0) s_base = atomicAdd(out_cnt, s_n);
    __syncthreads();
    int* out_list = out_list0 + ((size_t)t * B + b) * out_bstride;
    for (int j = tid; j < s_n; j += 256) out_list[s_base + j] = s_list[j];
    __syncthreads();
  }
  if constexpr (POOL) {  // unpooled spike-count partial (for sum_sp): 1 atomic per block
    if (tid == 0) s_uc = 0;
    __syncthreads();
    if ((tid & 63) == 0 && wcount) atomicAdd(&s_uc, wcount);
    __syncthreads();
    if (tid == 0 && s_uc) atomicAdd(sump_layer + b, (float)s_uc);
  }
}

// one kernel per fc layer: thread owns one output neuron; block-staged compaction
template <int IN, int OUT>
__global__ __launch_bounds__(256) void k_fc_seq(const float* __restrict__ w,
                                                int* __restrict__ cnt, int in_ci, int out_ci,
                                                const int* __restrict__ in_list0, int in_bstride,
                                                int* __restrict__ out_list0, int out_bstride) {
  __shared__ int s_list[256];
  __shared__ int s_n, s_base;
  const int tid = threadIdx.x;
  const int q = blockIdx.x * 256 + tid;  // OUT % 256 == 0: block never crosses a batch
  const int b = q >> ilog2(OUT);
  const int o = q & (OUT - 1);
  float um = 0.0f, us = 0.0f, sav = 1.0f;
  bool active = false;
  for (int t = 0; t < 8; ++t) {
    const int S = ldcnt(cnt + (t * 8 + in_ci) * 8 + b);
    if (!active && S == 0) continue;
    active = true;
    if (tid == 0) s_n = 0;
    __syncthreads();
    const int* list = in_list0 + ((size_t)t * B + b) * in_bstride;
    float acc = 0.0f;
    for (int s = 0; s < S; ++s) acc += w[(size_t)o * IN + list[s]];
    float m = DM * um + acc;
    float s2 = DS * us + acc;
    um = m;
    us = s2;
    float u = sav * (m - s2);
    bool sp = (u - 1.0f > 0.0f);
    if (sp) sav = 0.0f;
    block_stage(sp, o, s_list, &s_n);
    __syncthreads();
    if (tid == 0 && s_n > 0) s_base = atomicAdd(cnt + (t * 8 + out_ci) * 8 + b, s_n);
    __syncthreads();
    int* out_list = out_list0 + ((size_t)t * B + b) * out_bstride;
    for (int j = tid; j < s_n; j += 256) out_list[s_base + j] = s_list[j];
    __syncthreads();
  }
}

// final FC (512->10) + te/out_t/out_u epilogue + sum_sp reduction from counters/partials
__global__ void k_fc3_seq(const float* __restrict__ w, int* __restrict__ cnt, int in_ci,
                          const int* __restrict__ in_list0, int in_bstride,
                          const float* __restrict__ sump, float* __restrict__ out) {
  __shared__ int s_c3;
  const int tid = threadIdx.x;  // 128 threads (2 waves)
  if (tid == 0) s_c3 = 0;
  __syncthreads();
  const bool lane_ok = (tid < 80);
  const int b = lane_ok ? tid / 10 : 0;
  const int o = lane_ok ? tid - b * 10 : 0;
  float um = 0.0f, us = 0.0f, sav = 1.0f, te = 0.0f, ot = 8.0f, ou = 0.0f;
  bool active = false;
  for (int t = 0; t < 8; ++t) {
    const int S = lane_ok ? ldcnt(cnt + (t * 8 + in_ci) * 8 + b) : 0;
    if (!active && !__any(S > 0)) continue;  // per-wave gate; inactive lanes are exact no-ops
    active = true;
    const int* list = in_list0 + ((size_t)t * B + b) * in_bstride;
    float acc = 0.0f;
    for (int s = 0; s < S; ++s) acc += w[o * 512 + list[s]];
    float m = DM * um + acc;
    float s2 = DS * us + acc;
    um = m;
    us = s2;
    float u = sav * (m - s2);
    bool sp = lane_ok && (u - 1.0f > 0.0f);
    if (sp) sav = 0.0f;
    float act = (u != 0.0f) ? 1.0f : 0.0f;
    te = te + (((te + act) != 0.0f) ? 1.0f : 0.0f);
    if (sp) {
      ot += te - 8.0f;  // out_t (dodt forward)
      ou += u;          // out_u
    }
    unsigned long long bal = __ballot(sp);
    if ((tid & 63) == 0 && bal) atomicAdd(&s_c3, (int)__popcll(bal));
  }
  if (lane_ok) {
    out[tid] = ot;
    out[80 + tid] = ou;
  }
  __syncthreads();
  // sum_sp: layers {0,1,4,5,6,7} = list-counter sums; {2,3} = unpooled partials; 8 = s_c3
  if (tid < 8) {
    float s = 0.0f;
    if (tid == 2 || tid == 3) {
      const float* sp = sump + (tid - 2) * 8;
      for (int b2 = 0; b2 < 8; ++b2) s += sp[b2];
    } else {
      for (int t = 0; t < 8; ++t)
        for (int b2 = 0; b2 < 8; ++b2) s += (float)cnt[(t * 8 + tid) * 8 + b2];
    }
    out[160 + tid] = s;
  }
  if (tid == 0) out[168] = (float)s_c3;
}

extern "C" void kernel_launch(void* const* d_in, const int* in_sizes, int n_in, void* d_out,
                              int out_size, void* d_ws, size_t ws_size, hipStream_t stream) {
  const float* input = (const float*)d_in[0];
  const float* wc1 = (const float*)d_in[1];
  const float* wc2 = (const float*)d_in[2];
  const float* wc3 = (const float*)d_in[3];
  const float* wc4 = (const float*)d_in[4];
  const float* wc5 = (const float*)d_in[5];
  const float* wf1 = (const float*)d_in[6];
  const float* wf2 = (const float*)d_in[7];
  const float* wf3 = (const float*)d_in[8];
  float* out = (float*)d_out;
  int* iws = (int*)d_ws;
  int* cnt = iws + I_CNT;
  float* sump = (float*)(iws + I_SUMP);
  if (ws_size < WS_NEED) return;  // ~43 MB needed

  k_init<<<1, 528, 0, stream>>>(cnt);
  k_encode<<<N_IN / 256, 256, 0, stream>>>(input, iws);
  k_conv_seq<3, 64, 32, 32, false><<<B * 64, 256, 0, stream>>>(
      wc1, cnt, 0, 1, iws + I_L0, BS_L0, iws + I_L1, BS_L1, nullptr);
  k_conv_seq<64, 128, 32, 32, true><<<B * 128, 256, 0, stream>>>(
      wc2, cnt, 1, 2, iws + I_L1, BS_L1, iws + I_P1, BS_P1, sump + 0);
  k_conv_seq<128, 256, 16, 16, true><<<B * 256, 256, 0, stream>>>(
      wc3, cnt, 2, 3, iws + I_P1, BS_P1, iws + I_P2, BS_P2, sump + 8);
  k_conv_seq<256, 512, 8, 8, false><<<B * 512, 256, 0, stream>>>(
      wc4, cnt, 3, 4, iws + I_P2, BS_P2, iws + I_L4, BS_L4, nullptr);
  k_conv_seq<512, 256, 8, 8, false><<<B * 256, 256, 0, stream>>>(
      wc5, cnt, 4, 5, iws + I_L4, BS_L4, iws + I_L5, BS_L5, nullptr);
  k_fc_seq<16384, 1024><<<B * 1024 / 256, 256, 0, stream>>>(
      wf1, cnt, 5, 6, iws + I_L5, BS_L5, iws + I_F1, BS_F1);
  k_fc_seq<1024, 512><<<B * 512 / 256, 256, 0, stream>>>(
      wf2, cnt, 6, 7, iws + I_F1, BS_F1, iws + I_F2, BS_F2);
  k_fc3_seq<<<1, 128, 0, stream>>>(wf3, cnt, 7, iws + I_F2, BS_F2, sump, out);
}